// Round 9
// baseline (248.042 us; speedup 1.0000x reference)
//
#include <hip/hip_runtime.h>
#include <float.h>

#define Bn 2
#define Nn 8192
#define Rr 2048
#define Kk 16
#define CIN 64
#define CL 16
#define COUT 128
#define K2c 256
#define GT (Bn*Rr)      // 4096 groups
#define FD (CL+CIN)     // 80
#define KC (Kk*FD)      // 1280
#define MGB 8           // mlp groups per block (8 groups, 8 waves, 512 thr)
#define SPLITK 4        // gemm split-K
#define CCAP 128        // knn candidate cap; expected count ~53 (v5.1 statistic)

// ---------------- prep: weight transposes / permute + pts4 packing ----------------
__global__ __launch_bounds__(256) void prep_kernel(
    const float* __restrict__ t1_w, const float* __restrict__ t2_w,
    const float* __restrict__ t3_w, const float* __restrict__ conv_w,
    const float* __restrict__ points,
    float* __restrict__ t1t, float* __restrict__ t2t,
    float* __restrict__ t3t, float* __restrict__ wp,
    float4* __restrict__ pts4)
{
  int i = blockIdx.x * 256 + threadIdx.x;
  if (i < K2c*48) { int j = i / 48, k = i - j*48; t1t[k*K2c + j] = t1_w[i]; }
  if (i < K2c*K2c) { int j = i >> 8, k = i & 255; t2t[k*K2c + j] = t2_w[i]; t3t[k*K2c + j] = t3_w[i]; }
  if (i < COUT*KC) {
    int o = i / KC, ck = i - o*KC;
    int c = ck >> 4, k = ck & 15;
    wp[(k*FD + c)*COUT + o] = conv_w[i];
  }
  if (i < Bn*Nn) {
    float x = points[i*3+0], y = points[i*3+1], z = points[i*3+2];
    // numpy order: sq = (x*x + y*y) + z*z, muls materialized then summed
    float sq = __fadd_rn(__fadd_rn(__fmul_rn(x,x), __fmul_rn(y,y)), __fmul_rn(z,z));
    pts4[i] = make_float4(x, y, z, sq);
  }
}

// ---------------- knn v9 (unchanged, harness-verified): streamed points ----------------
__global__ __launch_bounds__(512, 4) void knn_kernel(
    const float4* __restrict__ pts4, const int* __restrict__ rep_idx,
    int* __restrict__ nb_idx, float* __restrict__ p_out,
    float* __restrict__ rep_pos_out)
{
  __shared__ float cbuf[8][512];                 // 16 KB per-thread minima [q][t]
  __shared__ unsigned long long coll[8][CCAP];   // 8 KB candidates
  __shared__ float Lst[8][64];                   // 2 KB per-lane tau stats
  __shared__ float4 qS[8];
  __shared__ float  tauS[8];
  __shared__ int    ccnt[8];

  int t    = threadIdx.x;
  int lane = t & 63;
  int w    = t >> 6;                 // 0..7
  int g0   = blockIdx.x * 8;         // 8 | 2048: block never straddles batches
  int b    = g0 >> 11;
  const float4* pb4 = pts4 + (size_t)b*Nn;

  if (t < 8) {
    int g = g0 + t;
    int r = g & 2047;
    qS[t] = pb4[rep_idx[r]];
    ccnt[t] = 0;
  }
  __syncthreads();

  // queries to SGPRs (uniform across block)
  float qx[8], qy[8], qz[8], qw[8];
  #pragma unroll
  for (int q = 0; q < 8; q++) {
    float4 Q = qS[q];
    qx[q] = __uint_as_float(__builtin_amdgcn_readfirstlane(__float_as_uint(Q.x)));
    qy[q] = __uint_as_float(__builtin_amdgcn_readfirstlane(__float_as_uint(Q.y)));
    qz[q] = __uint_as_float(__builtin_amdgcn_readfirstlane(__float_as_uint(Q.z)));
    qw[q] = __uint_as_float(__builtin_amdgcn_readfirstlane(__float_as_uint(Q.w)));
  }

  // ---- pass 1: per-thread min d2 per query; points streamed 4-at-a-time ----
  float m[8];
  #pragma unroll
  for (int q = 0; q < 8; q++) m[q] = FLT_MAX;
  for (int i0 = 0; i0 < 16; i0 += 4) {
    float4 P0 = pb4[t + 512*(i0+0)];
    float4 P1 = pb4[t + 512*(i0+1)];
    float4 P2 = pb4[t + 512*(i0+2)];
    float4 P3 = pb4[t + 512*(i0+3)];
    #pragma unroll
    for (int q = 0; q < 8; q++) {
      float d0 = __fsub_rn(__fadd_rn(qw[q], P0.w), __fmul_rn(2.0f,
                 __fmaf_rn(qz[q], P0.z, __fmaf_rn(qy[q], P0.y, __fmul_rn(qx[q], P0.x)))));
      float d1 = __fsub_rn(__fadd_rn(qw[q], P1.w), __fmul_rn(2.0f,
                 __fmaf_rn(qz[q], P1.z, __fmaf_rn(qy[q], P1.y, __fmul_rn(qx[q], P1.x)))));
      float d2 = __fsub_rn(__fadd_rn(qw[q], P2.w), __fmul_rn(2.0f,
                 __fmaf_rn(qz[q], P2.z, __fmaf_rn(qy[q], P2.y, __fmul_rn(qx[q], P2.x)))));
      float d3 = __fsub_rn(__fadd_rn(qw[q], P3.w), __fmul_rn(2.0f,
                 __fmaf_rn(qz[q], P3.z, __fmaf_rn(qy[q], P3.y, __fmul_rn(qx[q], P3.x)))));
      m[q] = fminf(fminf(fminf(m[q], d0), fminf(d1, d2)), d3);
    }
  }

  #pragma unroll
  for (int q = 0; q < 8; q++) cbuf[q][t] = m[q];
  __syncthreads();

  // ---- tau: wave w handles query w ----
  {
    // per-lane 3rd-smallest of its 8 thread-minima (bounds 3 real distances)
    float C0 = FLT_MAX, C1 = FLT_MAX, C2 = FLT_MAX;
    #pragma unroll
    for (int j = 0; j < 8; j++) {
      float v = cbuf[w][lane + 64*j];
      float n2 = __builtin_amdgcn_fmed3f(C1, C2, v);
      float n1 = __builtin_amdgcn_fmed3f(C0, C1, v);
      float n0 = fminf(C0, v);
      C0 = n0; C1 = n1; C2 = n2;
    }
    Lst[w][lane] = C2;
  }
  __syncthreads();
  {
    // tau = 6th-smallest L (rank 5, lex (L,lane) unique) -> >=18 pts <= tau
    float L = Lst[w][lane];
    int rk = 0;
    #pragma unroll 8
    for (int i = 0; i < 64; i++) {
      float Li = Lst[w][i];
      rk += (Li < L || (Li == L && i < lane)) ? 1 : 0;
    }
    if (rk == 5) tauS[w] = L;
  }
  __syncthreads();

  float tau[8];
  #pragma unroll
  for (int q = 0; q < 8; q++)
    tau[q] = __uint_as_float(__builtin_amdgcn_readfirstlane(__float_as_uint(tauS[q])));

  // ---- pass 2: re-stream points (L2-hot), predicate + collect ----
  for (int i0 = 0; i0 < 16; i0 += 4) {
    float4 Pb[4];
    Pb[0] = pb4[t + 512*(i0+0)];
    Pb[1] = pb4[t + 512*(i0+1)];
    Pb[2] = pb4[t + 512*(i0+2)];
    Pb[3] = pb4[t + 512*(i0+3)];
    #pragma unroll
    for (int u = 0; u < 4; u++) {
      float4 P = Pb[u];
      int idx = t + 512*(i0+u);
      #pragma unroll
      for (int q = 0; q < 8; q++) {
        float dot = __fmaf_rn(qz[q], P.z, __fmaf_rn(qy[q], P.y, __fmul_rn(qx[q], P.x)));
        float d2  = __fsub_rn(__fadd_rn(qw[q], P.w), __fmul_rn(2.0f, dot));
        if (d2 <= tau[q]) {
          int pos = atomicAdd(&ccnt[q], 1);
          if (pos < CCAP) {
            unsigned f = __float_as_uint(d2);
            unsigned mono = f ^ ((unsigned)((int)f >> 31) | 0x80000000u);
            coll[q][pos] = ((unsigned long long)mono << 32) | (unsigned)idx;
          }
        }
      }
    }
  }
  __syncthreads();

  // ---- extraction: exact rank via broadcast-compare (no serial chains) ----
  int cnt = __builtin_amdgcn_readfirstlane(ccnt[w]);
  if (cnt > CCAP) cnt = CCAP;
  unsigned long long k1 = (lane < cnt)      ? coll[w][lane]      : ~0ull;
  unsigned long long k2 = (lane + 64 < cnt) ? coll[w][lane + 64] : ~0ull;
  int r1 = 0, r2 = 0;
  for (int i = 0; i < cnt; i++) {
    unsigned long long ki = coll[w][i];   // broadcast read
    r1 += (ki < k1) ? 1 : 0;
    r2 += (ki < k2) ? 1 : 0;
  }

  int g = g0 + w;
  float4 Q = qS[w];
  if (lane < cnt && r1 >= 1 && r1 <= 16) {
    int om = (int)(k1 & 0xFFFFFFFFull);
    nb_idx[g*Kk + r1 - 1] = om;
    float4 Pm = pb4[om];
    p_out[(g*Kk + r1 - 1)*3 + 0] = __fsub_rn(Pm.x, Q.x);
    p_out[(g*Kk + r1 - 1)*3 + 1] = __fsub_rn(Pm.y, Q.y);
    p_out[(g*Kk + r1 - 1)*3 + 2] = __fsub_rn(Pm.z, Q.z);
  }
  if (lane + 64 < cnt && r2 >= 1 && r2 <= 16) {
    int om = (int)(k2 & 0xFFFFFFFFull);
    nb_idx[g*Kk + r2 - 1] = om;
    float4 Pm = pb4[om];
    p_out[(g*Kk + r2 - 1)*3 + 0] = __fsub_rn(Pm.x, Q.x);
    p_out[(g*Kk + r2 - 1)*3 + 1] = __fsub_rn(Pm.y, Q.y);
    p_out[(g*Kk + r2 - 1)*3 + 2] = __fsub_rn(Pm.z, Q.z);
  }
  if (lane < 3) rep_pos_out[g*3 + lane] = (lane == 0 ? Q.x : (lane == 1 ? Q.y : Q.z));
}

// ---------------- mlp_tf v14: depth-8 weight prefetch + single-phase reduction ----------------
// v13 counters: dur 44us, VALUBusy 42%, occupancy 34% (grid-limited 2 blk/CU),
// conflicts negligible, HBM 8.7%. Stall sources: (a) weight prefetch distance
// 4 KSTAGEs (~190 cy) vs L2 latency 200-300cy -> deepen to 8 buffers
// (distance 64 k-units ~ 380 cy, v11-proven); (b) two-phase reduction = extra
// barrier + LDS RMW round per layer -> single-phase: grid-limited at 2 blk/CU
// means LDS to 80KB is free, so red grows to 256x66 (66KB, all 8 waves write
// own rows), one barrier. REDUCE regroups the 8-way sum (pure FP re-assoc,
// threshold 0.14 >> 0.016). Per-thread k-visit order unchanged (ascending
// by 8). launch_bounds(512,4) pins VGPR<=128 to protect 16 waves/CU.
__device__ __forceinline__ void fma_g(float4& a, float hv, const float4& wv) {
  a.x = fmaf(hv, wv.x, a.x);
  a.y = fmaf(hv, wv.y, a.y);
  a.z = fmaf(hv, wv.z, a.z);
  a.w = fmaf(hv, wv.w, a.w);
}

__global__ __launch_bounds__(512, 4) void mlp_tf_kernel(
    const float* __restrict__ p,
    const float* __restrict__ t1t, const float* __restrict__ t1_b,
    const float* __restrict__ g1v, const float* __restrict__ b1v,
    const float* __restrict__ t2t, const float* __restrict__ t2_b,
    const float* __restrict__ g2v, const float* __restrict__ b2v,
    const float* __restrict__ t3t, const float* __restrict__ t3_b,
    const float* __restrict__ g3v, const float* __restrict__ b3v,
    const float* __restrict__ features, const int* __restrict__ nb_idx,
    const float* __restrict__ lift_w, const float* __restrict__ lift_b,
    const float* __restrict__ bng, const float* __restrict__ bnb,
    float* __restrict__ Tf)
{
  __shared__ float pf[48][MGB];      // 1.5 KB (= p transposed; also serves tf lift)
  __shared__ float hA[K2c][MGB];     // 8 KB (layer I/O; reused as T_s after layer 3)
  __shared__ float red[256*66];      // 66 KB (single-phase reduction; f_s reuse in tf)
  __shared__ int   idxs[128];        // 512 B (8 groups x 16 neighbors)
  __shared__ float lw[48], lb2[16], lg[16], lo[16];
  int t = threadIdx.x;
  int w = t >> 6, l = t & 63;
  int g0 = blockIdx.x * MGB;
  int bb_ = g0 / Rr;                 // batch (8 | 2048: never straddles)
  for (int e = t; e < MGB*48; e += 512) {
    int g = e / 48, k = e - g*48;
    pf[k][g] = p[(size_t)(g0+g)*48 + k];
  }
  if (t < 128) idxs[t] = nb_idx[g0*16 + t];
  else if (t >= 128 && t < 176) lw[t-128]  = lift_w[t-128];
  else if (t >= 176 && t < 192) lb2[t-176] = lift_b[t-176];
  else if (t >= 192 && t < 208) lg[t-192]  = bng[t-192];
  else if (t >= 208 && t < 224) lo[t-208]  = bnb[t-208];
  __syncthreads();

  float4 acc[MGB];   // acc[q] = group q over cols 4l..4l+3
  int col = t & 255; // output neuron this thread reduces/writes
  int h   = t >> 8;  // group-half (0: q0..3, 1: q4..7)
  int cc  = col & 3, lr = col >> 2;

#define LDW(WSRC, K) (*(const float4*)&WSRC[(size_t)(K)*K2c + 4*l])

#define KSTAGE(WSRC, KDIM, HBUF, WB, KK, KNEXT)                        \
  {                                                                    \
    float4 wc = WB;                                                    \
    if ((KNEXT) < KDIM) WB = LDW(WSRC, KNEXT);                         \
    float4 ha = *(const float4*)&HBUF[KK][0];                          \
    float4 hb = *(const float4*)&HBUF[KK][4];                          \
    fma_g(acc[0], ha.x, wc); fma_g(acc[1], ha.y, wc);                  \
    fma_g(acc[2], ha.z, wc); fma_g(acc[3], ha.w, wc);                  \
    fma_g(acc[4], hb.x, wc); fma_g(acc[5], hb.y, wc);                  \
    fma_g(acc[6], hb.z, wc); fma_g(acc[7], hb.w, wc);                  \
  }

#define KLOOP(WSRC, KDIM, HBUF)                                        \
  {                                                                    \
    _Pragma("unroll")                                                  \
    for (int q = 0; q < MGB; q++) acc[q] = make_float4(0.f,0.f,0.f,0.f);\
    float4 wb0 = LDW(WSRC, w);                                         \
    float4 wb1 = (w + 8  < KDIM) ? LDW(WSRC, w + 8)  : wb0;            \
    float4 wb2 = (w + 16 < KDIM) ? LDW(WSRC, w + 16) : wb0;            \
    float4 wb3 = (w + 24 < KDIM) ? LDW(WSRC, w + 24) : wb0;            \
    float4 wb4 = (w + 32 < KDIM) ? LDW(WSRC, w + 32) : wb0;            \
    float4 wb5 = (w + 40 < KDIM) ? LDW(WSRC, w + 40) : wb0;            \
    float4 wb6 = (w + 48 < KDIM) ? LDW(WSRC, w + 48) : wb0;            \
    float4 wb7 = (w + 56 < KDIM) ? LDW(WSRC, w + 56) : wb0;            \
    for (int k = w; k < KDIM; k += 64) {                               \
      KSTAGE(WSRC, KDIM, HBUF, wb0, k,      k + 64)                    \
      if (k + 8  < KDIM) KSTAGE(WSRC, KDIM, HBUF, wb1, k + 8,  k + 72) \
      if (k + 16 < KDIM) KSTAGE(WSRC, KDIM, HBUF, wb2, k + 16, k + 80) \
      if (k + 24 < KDIM) KSTAGE(WSRC, KDIM, HBUF, wb3, k + 24, k + 88) \
      if (k + 32 < KDIM) KSTAGE(WSRC, KDIM, HBUF, wb4, k + 32, k + 96) \
      if (k + 40 < KDIM) KSTAGE(WSRC, KDIM, HBUF, wb5, k + 40, k + 104)\
      if (k + 48 < KDIM) KSTAGE(WSRC, KDIM, HBUF, wb6, k + 48, k + 112)\
      if (k + 56 < KDIM) KSTAGE(WSRC, KDIM, HBUF, wb7, k + 56, k + 120)\
    }                                                                  \
  }

// single-phase: all 8 waves write their own rows, one barrier
#define WRITE_RED()                                                    \
  {                                                                    \
    _Pragma("unroll")                                                  \
    for (int q = 0; q < MGB; q++) {                                    \
      red[((w*4 + 0)*8 + q)*66 + l] = acc[q].x;                        \
      red[((w*4 + 1)*8 + q)*66 + l] = acc[q].y;                        \
      red[((w*4 + 2)*8 + q)*66 + l] = acc[q].z;                        \
      red[((w*4 + 3)*8 + q)*66 + l] = acc[q].w;                        \
    }                                                                  \
    __syncthreads();                                                   \
  }

// thread t sums 8 ww-rows for its (col, group-half): S[qi] = out[col, h*4+qi]
#define REDUCE(S)                                                      \
  float S[4] = {0.f, 0.f, 0.f, 0.f};                                   \
  {                                                                    \
    _Pragma("unroll")                                                  \
    for (int ww = 0; ww < 8; ww++) {                                   \
      _Pragma("unroll")                                                \
      for (int qi = 0; qi < 4; qi++)                                   \
        S[qi] += red[((ww*4 + cc)*8 + (h*4 + qi))*66 + lr];            \
    }                                                                  \
  }

  // ===== layer 1 (K=48), relu =====
  KLOOP(t1t, 48, pf)
  WRITE_RED()
  {
    REDUCE(s)
    float bb = t1_b[col], gg = g1v[col], oo = b1v[col];
    float4 v;
    v.x = fmaxf(fmaf(s[0] + bb, gg, oo), 0.f);
    v.y = fmaxf(fmaf(s[1] + bb, gg, oo), 0.f);
    v.z = fmaxf(fmaf(s[2] + bb, gg, oo), 0.f);
    v.w = fmaxf(fmaf(s[3] + bb, gg, oo), 0.f);
    *(float4*)&hA[col][h*4] = v;
  }
  __syncthreads();

  // ===== layer 2 (K=256), relu =====
  KLOOP(t2t, K2c, hA)
  WRITE_RED()
  {
    REDUCE(s)
    float bb = t2_b[col], gg = g2v[col], oo = b2v[col];
    float4 v;
    v.x = fmaxf(fmaf(s[0] + bb, gg, oo), 0.f);
    v.y = fmaxf(fmaf(s[1] + bb, gg, oo), 0.f);
    v.z = fmaxf(fmaf(s[2] + bb, gg, oo), 0.f);
    v.w = fmaxf(fmaf(s[3] + bb, gg, oo), 0.f);
    *(float4*)&hA[col][h*4] = v;
  }
  __syncthreads();

  // ===== layer 3 (K=256), no relu, T -> LDS (hA reused as T_s) =====
  KLOOP(t3t, K2c, hA)
  WRITE_RED()
  float* T_s = &hA[0][0];   // T_s[g*256 + col]; hA dead after last KLOOP
  {
    REDUCE(s)
    float bb = t3_b[col], gg = g3v[col], oo = b3v[col];
    #pragma unroll
    for (int qi = 0; qi < 4; qi++)
      T_s[(h*4 + qi)*K2c + col] = fmaf(s[qi] + bb, gg, oo);
  }
  __syncthreads();          // red reads done (f_s reuse safe), T_s visible

  // ===== tf phase: 4 groups per pass, 2 passes (f_s reuses red) =====
  float* f_s = red;         // f_s[gg4*KC + k*FD + c], 4*1280 floats = 20 KB
  for (int pass = 0; pass < 2; pass++) {
    // gather neighbor features: 64 rows (4 groups x 16 nbrs) x 64 ch
    for (int row = w; row < 64; row += 8) {
      int gg4 = row >> 4, k = row & 15;
      int gl = pass*4 + gg4;
      f_s[gg4*KC + k*FD + CL + l] =
          features[((size_t)bb_*Nn + idxs[gl*16 + k])*CIN + l];
    }
    // lifted BN+ReLU: 4*16*16 = 1024 elements
    for (int e = t; e < 1024; e += 512) {
      int gg4 = e >> 8, rem = e & 255, k = rem >> 4, c = rem & 15;
      int gl = pass*4 + gg4;
      float a = pf[k*3 + 0][gl]*lw[c*3+0] + pf[k*3 + 1][gl]*lw[c*3+1]
              + pf[k*3 + 2][gl]*lw[c*3+2] + lb2[c];
      a = a*lg[c] + lo[c];
      f_s[gg4*KC + k*FD + c] = fmaxf(a, 0.f);
    }
    __syncthreads();
    // T x feat: 2 waves per group (ci = sub*64 + lane)
    {
      int gg4 = w >> 1, sub = w & 1;
      int ci = sub*64 + l;
      if (ci < FD) {
        int gl = pass*4 + gg4;
        float fcol[16];
        #pragma unroll
        for (int j = 0; j < 16; j++) fcol[j] = f_s[gg4*KC + j*FD + ci];
        #pragma unroll
        for (int k = 0; k < 16; k++) {
          float a = 0.f;
          #pragma unroll
          for (int j = 0; j < 16; j++)
            a = fmaf(T_s[gl*K2c + k*16 + j], fcol[j], a);
          Tf[(size_t)(g0+gl)*KC + k*FD + ci] = a;
        }
      }
    }
    __syncthreads();        // f_s reads done before next pass overwrite
  }
#undef KLOOP
#undef KSTAGE
#undef LDW
#undef WRITE_RED
#undef REDUCE
}

// ---------------- gemm: out = Tf(4096x1280) @ Wp(1280x128), split-K=4 ----------------
__global__ __launch_bounds__(256) void gemm_kernel(
    const float* __restrict__ A,    // Tf
    const float* __restrict__ Bm,   // Wp
    float* __restrict__ part)       // [SPLITK][GT][COUT]
{
  __shared__ float As[16*36];
  __shared__ float Bs[16*COUT];
  int t = threadIdx.x;
  int m0 = blockIdx.x * 32;
  int ky = blockIdx.y;
  int kbase0 = ky * (KC/SPLITK);    // 320
  float acc[4][4];
  #pragma unroll
  for (int i = 0; i < 4; i++)
    #pragma unroll
    for (int j = 0; j < 4; j++) acc[i][j] = 0.f;
  int tn = t & 31, tm = t >> 5;

  for (int kt = 0; kt < KC/SPLITK; kt += 16) {
    int kb = kbase0 + kt;
    {
      int kcol = t & 15, row = t >> 4;
      As[kcol*36 + row]      = A[(size_t)(m0+row)*KC + kb + kcol];
      As[kcol*36 + row + 16] = A[(size_t)(m0+row+16)*KC + kb + kcol];
    }
    {
      int o = t & 127, kk2 = t >> 7;
      #pragma unroll
      for (int p4 = 0; p4 < 8; p4++) {
        int kk = kk2 + p4*2;
        Bs[kk*COUT + o] = Bm[(size_t)(kb+kk)*COUT + o];
      }
    }
    __syncthreads();
    #pragma unroll
    for (int kk = 0; kk < 16; kk++) {
      float4 a4 = *(const float4*)&As[kk*36 + tm*4];
      float4 b4 = *(const float4*)&Bs[kk*COUT + tn*4];
      float av[4] = {a4.x, a4.y, a4.z, a4.w};
      float bv[4] = {b4.x, b4.y, b4.z, b4.w};
      #pragma unroll
      for (int i = 0; i < 4; i++)
        #pragma unroll
        for (int j = 0; j < 4; j++) acc[i][j] = fmaf(av[i], bv[j], acc[i][j]);
    }
    __syncthreads();
  }
  #pragma unroll
  for (int i = 0; i < 4; i++) {
    float4 v = make_float4(acc[i][0], acc[i][1], acc[i][2], acc[i][3]);
    *(float4*)&part[((size_t)ky*GT + m0 + tm*4 + i)*COUT + tn*4] = v;
  }
}

// ---------------- reduce: out = sum(part[0..SPLITK-1]) + bias ----------------
__global__ __launch_bounds__(256) void reduce_kernel(
    const float* __restrict__ part, const float* __restrict__ conv_b,
    float* __restrict__ outp)
{
  int i = blockIdx.x*256 + threadIdx.x;
  float4 s = ((const float4*)conv_b)[i & 31];
  #pragma unroll
  for (int w = 0; w < SPLITK; w++) {
    float4 v = ((const float4*)(part + (size_t)w*GT*COUT))[i];
    s.x += v.x; s.y += v.y; s.z += v.z; s.w += v.w;
  }
  ((float4*)outp)[i] = s;
}

extern "C" void kernel_launch(void* const* d_in, const int* in_sizes, int n_in,
                              void* d_out, int out_size, void* d_ws, size_t ws_size,
                              hipStream_t stream) {
  const float* points   = (const float*)d_in[0];
  const float* features = (const float*)d_in[1];
  const float* lift_w   = (const float*)d_in[2];
  const float* lift_b   = (const float*)d_in[3];
  const float* bn_lift_g= (const float*)d_in[4];
  const float* bn_lift_b= (const float*)d_in[5];
  const float* t1_w     = (const float*)d_in[6];
  const float* t1_b     = (const float*)d_in[7];
  const float* bn1_g    = (const float*)d_in[8];
  const float* bn1_b    = (const float*)d_in[9];
  const float* t2_w     = (const float*)d_in[10];
  const float* t2_b     = (const float*)d_in[11];
  const float* bn2_g    = (const float*)d_in[12];
  const float* bn2_b    = (const float*)d_in[13];
  const float* t3_w     = (const float*)d_in[14];
  const float* t3_b     = (const float*)d_in[15];
  const float* bn3_g    = (const float*)d_in[16];
  const float* bn3_b    = (const float*)d_in[17];
  const float* conv_w   = (const float*)d_in[18];
  const float* conv_b   = (const float*)d_in[19];
  const int*   rep_idx  = (const int*)d_in[20];

  char* ws = (char*)d_ws;
  int*    nb   = (int*)   (ws + 0);          // 256 KB
  float*  p    = (float*) (ws + 262144);     // 768 KB
  float*  Tf   = (float*) (ws + 5242880);    // 20 MB
  float*  wp   = (float*) (ws + 26214400);   // 640 KB
  float*  t1t  = (float*) (ws + 26869760);   // 48 KB
  float*  t2t  = (float*) (ws + 26918912);   // 256 KB
  float*  t3t  = (float*) (ws + 27181056);   // 256 KB
  float*  part = (float*) (ws + 33554432);   // 8 MB (SPLITK=4)
  float4* pts4 = (float4*)(ws + 52428800);   // 256 KB

  float* rep_pos = (float*)d_out;
  float* outp    = (float*)d_out + (size_t)GT*3;

  prep_kernel<<<640, 256, 0, stream>>>(t1_w, t2_w, t3_w, conv_w, points,
                                       t1t, t2t, t3t, wp, pts4);
  knn_kernel<<<GT/8, 512, 0, stream>>>(pts4, rep_idx, nb, p, rep_pos);
  mlp_tf_kernel<<<GT/MGB, 512, 0, stream>>>(p, t1t, t1_b, bn1_g, bn1_b,
                                            t2t, t2_b, bn2_g, bn2_b,
                                            t3t, t3_b, bn3_g, bn3_b,
                                            features, nb,
                                            lift_w, lift_b, bn_lift_g, bn_lift_b,
                                            Tf);
  dim3 ggrid(GT/32, SPLITK);
  gemm_kernel<<<ggrid, 256, 0, stream>>>(Tf, wp, part);
  reduce_kernel<<<(GT*COUT/4)/256, 256, 0, stream>>>(part, conv_b, outp);
}

// Round 10
// 205.631 us; speedup vs baseline: 1.2063x; 1.2063x over previous
//
#include <hip/hip_runtime.h>
#include <float.h>

#define Bn 2
#define Nn 8192
#define Rr 2048
#define Kk 16
#define CIN 64
#define CL 16
#define COUT 128
#define K2c 256
#define GT (Bn*Rr)      // 4096 groups
#define FD (CL+CIN)     // 80
#define KC (Kk*FD)      // 1280
#define MGB 8           // mlp groups per block (8 groups, 8 waves, 512 thr)
#define SPLITK 4        // gemm split-K
#define CCAP 128        // knn candidate cap; expected count ~53 (v5.1 statistic)

// ---------------- prep: weight transposes / permute + pts4 packing ----------------
__global__ __launch_bounds__(256) void prep_kernel(
    const float* __restrict__ t1_w, const float* __restrict__ t2_w,
    const float* __restrict__ t3_w, const float* __restrict__ conv_w,
    const float* __restrict__ points,
    float* __restrict__ t1t, float* __restrict__ t2t,
    float* __restrict__ t3t, float* __restrict__ wp,
    float4* __restrict__ pts4)
{
  int i = blockIdx.x * 256 + threadIdx.x;
  if (i < K2c*48) { int j = i / 48, k = i - j*48; t1t[k*K2c + j] = t1_w[i]; }
  if (i < K2c*K2c) { int j = i >> 8, k = i & 255; t2t[k*K2c + j] = t2_w[i]; t3t[k*K2c + j] = t3_w[i]; }
  if (i < COUT*KC) {
    int o = i / KC, ck = i - o*KC;
    int c = ck >> 4, k = ck & 15;
    wp[(k*FD + c)*COUT + o] = conv_w[i];
  }
  if (i < Bn*Nn) {
    float x = points[i*3+0], y = points[i*3+1], z = points[i*3+2];
    // numpy order: sq = (x*x + y*y) + z*z, muls materialized then summed
    float sq = __fadd_rn(__fadd_rn(__fmul_rn(x,x), __fmul_rn(y,y)), __fmul_rn(z,z));
    pts4[i] = make_float4(x, y, z, sq);
  }
}

// ---------------- knn v9 (unchanged, harness-verified): streamed points ----------------
// NOTE: (512,4) caps VGPR at 64 on this toolchain (2nd arg = min BLOCKS/CU,
// CUDA-style: 4 blk x 8 waves = 32 waves/CU -> 2048/32 = 64). knn fits in 64.
__global__ __launch_bounds__(512, 4) void knn_kernel(
    const float4* __restrict__ pts4, const int* __restrict__ rep_idx,
    int* __restrict__ nb_idx, float* __restrict__ p_out,
    float* __restrict__ rep_pos_out)
{
  __shared__ float cbuf[8][512];                 // 16 KB per-thread minima [q][t]
  __shared__ unsigned long long coll[8][CCAP];   // 8 KB candidates
  __shared__ float Lst[8][64];                   // 2 KB per-lane tau stats
  __shared__ float4 qS[8];
  __shared__ float  tauS[8];
  __shared__ int    ccnt[8];

  int t    = threadIdx.x;
  int lane = t & 63;
  int w    = t >> 6;                 // 0..7
  int g0   = blockIdx.x * 8;         // 8 | 2048: block never straddles batches
  int b    = g0 >> 11;
  const float4* pb4 = pts4 + (size_t)b*Nn;

  if (t < 8) {
    int g = g0 + t;
    int r = g & 2047;
    qS[t] = pb4[rep_idx[r]];
    ccnt[t] = 0;
  }
  __syncthreads();

  // queries to SGPRs (uniform across block)
  float qx[8], qy[8], qz[8], qw[8];
  #pragma unroll
  for (int q = 0; q < 8; q++) {
    float4 Q = qS[q];
    qx[q] = __uint_as_float(__builtin_amdgcn_readfirstlane(__float_as_uint(Q.x)));
    qy[q] = __uint_as_float(__builtin_amdgcn_readfirstlane(__float_as_uint(Q.y)));
    qz[q] = __uint_as_float(__builtin_amdgcn_readfirstlane(__float_as_uint(Q.z)));
    qw[q] = __uint_as_float(__builtin_amdgcn_readfirstlane(__float_as_uint(Q.w)));
  }

  // ---- pass 1: per-thread min d2 per query; points streamed 4-at-a-time ----
  float m[8];
  #pragma unroll
  for (int q = 0; q < 8; q++) m[q] = FLT_MAX;
  for (int i0 = 0; i0 < 16; i0 += 4) {
    float4 P0 = pb4[t + 512*(i0+0)];
    float4 P1 = pb4[t + 512*(i0+1)];
    float4 P2 = pb4[t + 512*(i0+2)];
    float4 P3 = pb4[t + 512*(i0+3)];
    #pragma unroll
    for (int q = 0; q < 8; q++) {
      float d0 = __fsub_rn(__fadd_rn(qw[q], P0.w), __fmul_rn(2.0f,
                 __fmaf_rn(qz[q], P0.z, __fmaf_rn(qy[q], P0.y, __fmul_rn(qx[q], P0.x)))));
      float d1 = __fsub_rn(__fadd_rn(qw[q], P1.w), __fmul_rn(2.0f,
                 __fmaf_rn(qz[q], P1.z, __fmaf_rn(qy[q], P1.y, __fmul_rn(qx[q], P1.x)))));
      float d2 = __fsub_rn(__fadd_rn(qw[q], P2.w), __fmul_rn(2.0f,
                 __fmaf_rn(qz[q], P2.z, __fmaf_rn(qy[q], P2.y, __fmul_rn(qx[q], P2.x)))));
      float d3 = __fsub_rn(__fadd_rn(qw[q], P3.w), __fmul_rn(2.0f,
                 __fmaf_rn(qz[q], P3.z, __fmaf_rn(qy[q], P3.y, __fmul_rn(qx[q], P3.x)))));
      m[q] = fminf(fminf(fminf(m[q], d0), fminf(d1, d2)), d3);
    }
  }

  #pragma unroll
  for (int q = 0; q < 8; q++) cbuf[q][t] = m[q];
  __syncthreads();

  // ---- tau: wave w handles query w ----
  {
    // per-lane 3rd-smallest of its 8 thread-minima (bounds 3 real distances)
    float C0 = FLT_MAX, C1 = FLT_MAX, C2 = FLT_MAX;
    #pragma unroll
    for (int j = 0; j < 8; j++) {
      float v = cbuf[w][lane + 64*j];
      float n2 = __builtin_amdgcn_fmed3f(C1, C2, v);
      float n1 = __builtin_amdgcn_fmed3f(C0, C1, v);
      float n0 = fminf(C0, v);
      C0 = n0; C1 = n1; C2 = n2;
    }
    Lst[w][lane] = C2;
  }
  __syncthreads();
  {
    // tau = 6th-smallest L (rank 5, lex (L,lane) unique) -> >=18 pts <= tau
    float L = Lst[w][lane];
    int rk = 0;
    #pragma unroll 8
    for (int i = 0; i < 64; i++) {
      float Li = Lst[w][i];
      rk += (Li < L || (Li == L && i < lane)) ? 1 : 0;
    }
    if (rk == 5) tauS[w] = L;
  }
  __syncthreads();

  float tau[8];
  #pragma unroll
  for (int q = 0; q < 8; q++)
    tau[q] = __uint_as_float(__builtin_amdgcn_readfirstlane(__float_as_uint(tauS[q])));

  // ---- pass 2: re-stream points (L2-hot), predicate + collect ----
  for (int i0 = 0; i0 < 16; i0 += 4) {
    float4 Pb[4];
    Pb[0] = pb4[t + 512*(i0+0)];
    Pb[1] = pb4[t + 512*(i0+1)];
    Pb[2] = pb4[t + 512*(i0+2)];
    Pb[3] = pb4[t + 512*(i0+3)];
    #pragma unroll
    for (int u = 0; u < 4; u++) {
      float4 P = Pb[u];
      int idx = t + 512*(i0+u);
      #pragma unroll
      for (int q = 0; q < 8; q++) {
        float dot = __fmaf_rn(qz[q], P.z, __fmaf_rn(qy[q], P.y, __fmul_rn(qx[q], P.x)));
        float d2  = __fsub_rn(__fadd_rn(qw[q], P.w), __fmul_rn(2.0f, dot));
        if (d2 <= tau[q]) {
          int pos = atomicAdd(&ccnt[q], 1);
          if (pos < CCAP) {
            unsigned f = __float_as_uint(d2);
            unsigned mono = f ^ ((unsigned)((int)f >> 31) | 0x80000000u);
            coll[q][pos] = ((unsigned long long)mono << 32) | (unsigned)idx;
          }
        }
      }
    }
  }
  __syncthreads();

  // ---- extraction: exact rank via broadcast-compare (no serial chains) ----
  int cnt = __builtin_amdgcn_readfirstlane(ccnt[w]);
  if (cnt > CCAP) cnt = CCAP;
  unsigned long long k1 = (lane < cnt)      ? coll[w][lane]      : ~0ull;
  unsigned long long k2 = (lane + 64 < cnt) ? coll[w][lane + 64] : ~0ull;
  int r1 = 0, r2 = 0;
  for (int i = 0; i < cnt; i++) {
    unsigned long long ki = coll[w][i];   // broadcast read
    r1 += (ki < k1) ? 1 : 0;
    r2 += (ki < k2) ? 1 : 0;
  }

  int g = g0 + w;
  float4 Q = qS[w];
  if (lane < cnt && r1 >= 1 && r1 <= 16) {
    int om = (int)(k1 & 0xFFFFFFFFull);
    nb_idx[g*Kk + r1 - 1] = om;
    float4 Pm = pb4[om];
    p_out[(g*Kk + r1 - 1)*3 + 0] = __fsub_rn(Pm.x, Q.x);
    p_out[(g*Kk + r1 - 1)*3 + 1] = __fsub_rn(Pm.y, Q.y);
    p_out[(g*Kk + r1 - 1)*3 + 2] = __fsub_rn(Pm.z, Q.z);
  }
  if (lane + 64 < cnt && r2 >= 1 && r2 <= 16) {
    int om = (int)(k2 & 0xFFFFFFFFull);
    nb_idx[g*Kk + r2 - 1] = om;
    float4 Pm = pb4[om];
    p_out[(g*Kk + r2 - 1)*3 + 0] = __fsub_rn(Pm.x, Q.x);
    p_out[(g*Kk + r2 - 1)*3 + 1] = __fsub_rn(Pm.y, Q.y);
    p_out[(g*Kk + r2 - 1)*3 + 2] = __fsub_rn(Pm.z, Q.z);
  }
  if (lane < 3) rep_pos_out[g*3 + lane] = (lane == 0 ? Q.x : (lane == 1 ? Q.y : Q.z));
}

// ---------------- mlp_tf v15: v14 structure, launch bound fixed (512,2) ----------------
// v14 post-mortem: (512,4) caps VGPR at 64 on this toolchain (2nd arg acts as
// CUDA-style min-blocks/CU: 4 blk x 8 waves = 32 waves/CU -> 2048/32 = 64
// VGPR). Evidence: v8 knn AND v14 mlp_tf both reported exactly VGPR=64 +
// massive scratch traffic (172MB WRITE). Demand here ~95-100 (acc[8] + 8
// prefetch bufs) -> spilled. Fix: (512,2) -> 16 waves/CU -> 128-VGPR cap.
// Occupancy unchanged: grid 512 = exactly 2 blk/CU, LDS 78KB also allows 2.
// Depth-8 prefetch + single-phase reduction retained (v14 run verified their
// numerics: absmax identical 0.015625 through the spill).
__device__ __forceinline__ void fma_g(float4& a, float hv, const float4& wv) {
  a.x = fmaf(hv, wv.x, a.x);
  a.y = fmaf(hv, wv.y, a.y);
  a.z = fmaf(hv, wv.z, a.z);
  a.w = fmaf(hv, wv.w, a.w);
}

__global__ __launch_bounds__(512, 2) void mlp_tf_kernel(
    const float* __restrict__ p,
    const float* __restrict__ t1t, const float* __restrict__ t1_b,
    const float* __restrict__ g1v, const float* __restrict__ b1v,
    const float* __restrict__ t2t, const float* __restrict__ t2_b,
    const float* __restrict__ g2v, const float* __restrict__ b2v,
    const float* __restrict__ t3t, const float* __restrict__ t3_b,
    const float* __restrict__ g3v, const float* __restrict__ b3v,
    const float* __restrict__ features, const int* __restrict__ nb_idx,
    const float* __restrict__ lift_w, const float* __restrict__ lift_b,
    const float* __restrict__ bng, const float* __restrict__ bnb,
    float* __restrict__ Tf)
{
  __shared__ float pf[48][MGB];      // 1.5 KB (= p transposed; also serves tf lift)
  __shared__ float hA[K2c][MGB];     // 8 KB (layer I/O; reused as T_s after layer 3)
  __shared__ float red[256*66];      // 66 KB (single-phase reduction; f_s reuse in tf)
  __shared__ int   idxs[128];        // 512 B (8 groups x 16 neighbors)
  __shared__ float lw[48], lb2[16], lg[16], lo[16];
  int t = threadIdx.x;
  int w = t >> 6, l = t & 63;
  int g0 = blockIdx.x * MGB;
  int bb_ = g0 / Rr;                 // batch (8 | 2048: never straddles)
  for (int e = t; e < MGB*48; e += 512) {
    int g = e / 48, k = e - g*48;
    pf[k][g] = p[(size_t)(g0+g)*48 + k];
  }
  if (t < 128) idxs[t] = nb_idx[g0*16 + t];
  else if (t >= 128 && t < 176) lw[t-128]  = lift_w[t-128];
  else if (t >= 176 && t < 192) lb2[t-176] = lift_b[t-176];
  else if (t >= 192 && t < 208) lg[t-192]  = bng[t-192];
  else if (t >= 208 && t < 224) lo[t-208]  = bnb[t-208];
  __syncthreads();

  float4 acc[MGB];   // acc[q] = group q over cols 4l..4l+3
  int col = t & 255; // output neuron this thread reduces/writes
  int h   = t >> 8;  // group-half (0: q0..3, 1: q4..7)
  int cc  = col & 3, lr = col >> 2;

#define LDW(WSRC, K) (*(const float4*)&WSRC[(size_t)(K)*K2c + 4*l])

#define KSTAGE(WSRC, KDIM, HBUF, WB, KK, KNEXT)                        \
  {                                                                    \
    float4 wc = WB;                                                    \
    if ((KNEXT) < KDIM) WB = LDW(WSRC, KNEXT);                         \
    float4 ha = *(const float4*)&HBUF[KK][0];                          \
    float4 hb = *(const float4*)&HBUF[KK][4];                          \
    fma_g(acc[0], ha.x, wc); fma_g(acc[1], ha.y, wc);                  \
    fma_g(acc[2], ha.z, wc); fma_g(acc[3], ha.w, wc);                  \
    fma_g(acc[4], hb.x, wc); fma_g(acc[5], hb.y, wc);                  \
    fma_g(acc[6], hb.z, wc); fma_g(acc[7], hb.w, wc);                  \
  }

#define KLOOP(WSRC, KDIM, HBUF)                                        \
  {                                                                    \
    _Pragma("unroll")                                                  \
    for (int q = 0; q < MGB; q++) acc[q] = make_float4(0.f,0.f,0.f,0.f);\
    float4 wb0 = LDW(WSRC, w);                                         \
    float4 wb1 = (w + 8  < KDIM) ? LDW(WSRC, w + 8)  : wb0;            \
    float4 wb2 = (w + 16 < KDIM) ? LDW(WSRC, w + 16) : wb0;            \
    float4 wb3 = (w + 24 < KDIM) ? LDW(WSRC, w + 24) : wb0;            \
    float4 wb4 = (w + 32 < KDIM) ? LDW(WSRC, w + 32) : wb0;            \
    float4 wb5 = (w + 40 < KDIM) ? LDW(WSRC, w + 40) : wb0;            \
    float4 wb6 = (w + 48 < KDIM) ? LDW(WSRC, w + 48) : wb0;            \
    float4 wb7 = (w + 56 < KDIM) ? LDW(WSRC, w + 56) : wb0;            \
    for (int k = w; k < KDIM; k += 64) {                               \
      KSTAGE(WSRC, KDIM, HBUF, wb0, k,      k + 64)                    \
      if (k + 8  < KDIM) KSTAGE(WSRC, KDIM, HBUF, wb1, k + 8,  k + 72) \
      if (k + 16 < KDIM) KSTAGE(WSRC, KDIM, HBUF, wb2, k + 16, k + 80) \
      if (k + 24 < KDIM) KSTAGE(WSRC, KDIM, HBUF, wb3, k + 24, k + 88) \
      if (k + 32 < KDIM) KSTAGE(WSRC, KDIM, HBUF, wb4, k + 32, k + 96) \
      if (k + 40 < KDIM) KSTAGE(WSRC, KDIM, HBUF, wb5, k + 40, k + 104)\
      if (k + 48 < KDIM) KSTAGE(WSRC, KDIM, HBUF, wb6, k + 48, k + 112)\
      if (k + 56 < KDIM) KSTAGE(WSRC, KDIM, HBUF, wb7, k + 56, k + 120)\
    }                                                                  \
  }

// single-phase: all 8 waves write their own rows, one barrier
#define WRITE_RED()                                                    \
  {                                                                    \
    _Pragma("unroll")                                                  \
    for (int q = 0; q < MGB; q++) {                                    \
      red[((w*4 + 0)*8 + q)*66 + l] = acc[q].x;                        \
      red[((w*4 + 1)*8 + q)*66 + l] = acc[q].y;                        \
      red[((w*4 + 2)*8 + q)*66 + l] = acc[q].z;                        \
      red[((w*4 + 3)*8 + q)*66 + l] = acc[q].w;                        \
    }                                                                  \
    __syncthreads();                                                   \
  }

// thread t sums 8 ww-rows for its (col, group-half): S[qi] = out[col, h*4+qi]
#define REDUCE(S)                                                      \
  float S[4] = {0.f, 0.f, 0.f, 0.f};                                   \
  {                                                                    \
    _Pragma("unroll")                                                  \
    for (int ww = 0; ww < 8; ww++) {                                   \
      _Pragma("unroll")                                                \
      for (int qi = 0; qi < 4; qi++)                                   \
        S[qi] += red[((ww*4 + cc)*8 + (h*4 + qi))*66 + lr];            \
    }                                                                  \
  }

  // ===== layer 1 (K=48), relu =====
  KLOOP(t1t, 48, pf)
  WRITE_RED()
  {
    REDUCE(s)
    float bb = t1_b[col], gg = g1v[col], oo = b1v[col];
    float4 v;
    v.x = fmaxf(fmaf(s[0] + bb, gg, oo), 0.f);
    v.y = fmaxf(fmaf(s[1] + bb, gg, oo), 0.f);
    v.z = fmaxf(fmaf(s[2] + bb, gg, oo), 0.f);
    v.w = fmaxf(fmaf(s[3] + bb, gg, oo), 0.f);
    *(float4*)&hA[col][h*4] = v;
  }
  __syncthreads();

  // ===== layer 2 (K=256), relu =====
  KLOOP(t2t, K2c, hA)
  WRITE_RED()
  {
    REDUCE(s)
    float bb = t2_b[col], gg = g2v[col], oo = b2v[col];
    float4 v;
    v.x = fmaxf(fmaf(s[0] + bb, gg, oo), 0.f);
    v.y = fmaxf(fmaf(s[1] + bb, gg, oo), 0.f);
    v.z = fmaxf(fmaf(s[2] + bb, gg, oo), 0.f);
    v.w = fmaxf(fmaf(s[3] + bb, gg, oo), 0.f);
    *(float4*)&hA[col][h*4] = v;
  }
  __syncthreads();

  // ===== layer 3 (K=256), no relu, T -> LDS (hA reused as T_s) =====
  KLOOP(t3t, K2c, hA)
  WRITE_RED()
  float* T_s = &hA[0][0];   // T_s[g*256 + col]; hA dead after last KLOOP
  {
    REDUCE(s)
    float bb = t3_b[col], gg = g3v[col], oo = b3v[col];
    #pragma unroll
    for (int qi = 0; qi < 4; qi++)
      T_s[(h*4 + qi)*K2c + col] = fmaf(s[qi] + bb, gg, oo);
  }
  __syncthreads();          // red reads done (f_s reuse safe), T_s visible

  // ===== tf phase: 4 groups per pass, 2 passes (f_s reuses red) =====
  float* f_s = red;         // f_s[gg4*KC + k*FD + c], 4*1280 floats = 20 KB
  for (int pass = 0; pass < 2; pass++) {
    // gather neighbor features: 64 rows (4 groups x 16 nbrs) x 64 ch
    for (int row = w; row < 64; row += 8) {
      int gg4 = row >> 4, k = row & 15;
      int gl = pass*4 + gg4;
      f_s[gg4*KC + k*FD + CL + l] =
          features[((size_t)bb_*Nn + idxs[gl*16 + k])*CIN + l];
    }
    // lifted BN+ReLU: 4*16*16 = 1024 elements
    for (int e = t; e < 1024; e += 512) {
      int gg4 = e >> 8, rem = e & 255, k = rem >> 4, c = rem & 15;
      int gl = pass*4 + gg4;
      float a = pf[k*3 + 0][gl]*lw[c*3+0] + pf[k*3 + 1][gl]*lw[c*3+1]
              + pf[k*3 + 2][gl]*lw[c*3+2] + lb2[c];
      a = a*lg[c] + lo[c];
      f_s[gg4*KC + k*FD + c] = fmaxf(a, 0.f);
    }
    __syncthreads();
    // T x feat: 2 waves per group (ci = sub*64 + lane)
    {
      int gg4 = w >> 1, sub = w & 1;
      int ci = sub*64 + l;
      if (ci < FD) {
        int gl = pass*4 + gg4;
        float fcol[16];
        #pragma unroll
        for (int j = 0; j < 16; j++) fcol[j] = f_s[gg4*KC + j*FD + ci];
        #pragma unroll
        for (int k = 0; k < 16; k++) {
          float a = 0.f;
          #pragma unroll
          for (int j = 0; j < 16; j++)
            a = fmaf(T_s[gl*K2c + k*16 + j], fcol[j], a);
          Tf[(size_t)(g0+gl)*KC + k*FD + ci] = a;
        }
      }
    }
    __syncthreads();        // f_s reads done before next pass overwrite
  }
#undef KLOOP
#undef KSTAGE
#undef LDW
#undef WRITE_RED
#undef REDUCE
}

// ---------------- gemm: out = Tf(4096x1280) @ Wp(1280x128), split-K=4 ----------------
__global__ __launch_bounds__(256) void gemm_kernel(
    const float* __restrict__ A,    // Tf
    const float* __restrict__ Bm,   // Wp
    float* __restrict__ part)       // [SPLITK][GT][COUT]
{
  __shared__ float As[16*36];
  __shared__ float Bs[16*COUT];
  int t = threadIdx.x;
  int m0 = blockIdx.x * 32;
  int ky = blockIdx.y;
  int kbase0 = ky * (KC/SPLITK);    // 320
  float acc[4][4];
  #pragma unroll
  for (int i = 0; i < 4; i++)
    #pragma unroll
    for (int j = 0; j < 4; j++) acc[i][j] = 0.f;
  int tn = t & 31, tm = t >> 5;

  for (int kt = 0; kt < KC/SPLITK; kt += 16) {
    int kb = kbase0 + kt;
    {
      int kcol = t & 15, row = t >> 4;
      As[kcol*36 + row]      = A[(size_t)(m0+row)*KC + kb + kcol];
      As[kcol*36 + row + 16] = A[(size_t)(m0+row+16)*KC + kb + kcol];
    }
    {
      int o = t & 127, kk2 = t >> 7;
      #pragma unroll
      for (int p4 = 0; p4 < 8; p4++) {
        int kk = kk2 + p4*2;
        Bs[kk*COUT + o] = Bm[(size_t)(kb+kk)*COUT + o];
      }
    }
    __syncthreads();
    #pragma unroll
    for (int kk = 0; kk < 16; kk++) {
      float4 a4 = *(const float4*)&As[kk*36 + tm*4];
      float4 b4 = *(const float4*)&Bs[kk*COUT + tn*4];
      float av[4] = {a4.x, a4.y, a4.z, a4.w};
      float bv[4] = {b4.x, b4.y, b4.z, b4.w};
      #pragma unroll
      for (int i = 0; i < 4; i++)
        #pragma unroll
        for (int j = 0; j < 4; j++) acc[i][j] = fmaf(av[i], bv[j], acc[i][j]);
    }
    __syncthreads();
  }
  #pragma unroll
  for (int i = 0; i < 4; i++) {
    float4 v = make_float4(acc[i][0], acc[i][1], acc[i][2], acc[i][3]);
    *(float4*)&part[((size_t)ky*GT + m0 + tm*4 + i)*COUT + tn*4] = v;
  }
}

// ---------------- reduce: out = sum(part[0..SPLITK-1]) + bias ----------------
__global__ __launch_bounds__(256) void reduce_kernel(
    const float* __restrict__ part, const float* __restrict__ conv_b,
    float* __restrict__ outp)
{
  int i = blockIdx.x*256 + threadIdx.x;
  float4 s = ((const float4*)conv_b)[i & 31];
  #pragma unroll
  for (int w = 0; w < SPLITK; w++) {
    float4 v = ((const float4*)(part + (size_t)w*GT*COUT))[i];
    s.x += v.x; s.y += v.y; s.z += v.z; s.w += v.w;
  }
  ((float4*)outp)[i] = s;
}

extern "C" void kernel_launch(void* const* d_in, const int* in_sizes, int n_in,
                              void* d_out, int out_size, void* d_ws, size_t ws_size,
                              hipStream_t stream) {
  const float* points   = (const float*)d_in[0];
  const float* features = (const float*)d_in[1];
  const float* lift_w   = (const float*)d_in[2];
  const float* lift_b   = (const float*)d_in[3];
  const float* bn_lift_g= (const float*)d_in[4];
  const float* bn_lift_b= (const float*)d_in[5];
  const float* t1_w     = (const float*)d_in[6];
  const float* t1_b     = (const float*)d_in[7];
  const float* bn1_g    = (const float*)d_in[8];
  const float* bn1_b    = (const float*)d_in[9];
  const float* t2_w     = (const float*)d_in[10];
  const float* t2_b     = (const float*)d_in[11];
  const float* bn2_g    = (const float*)d_in[12];
  const float* bn2_b    = (const float*)d_in[13];
  const float* t3_w     = (const float*)d_in[14];
  const float* t3_b     = (const float*)d_in[15];
  const float* bn3_g    = (const float*)d_in[16];
  const float* bn3_b    = (const float*)d_in[17];
  const float* conv_w   = (const float*)d_in[18];
  const float* conv_b   = (const float*)d_in[19];
  const int*   rep_idx  = (const int*)d_in[20];

  char* ws = (char*)d_ws;
  int*    nb   = (int*)   (ws + 0);          // 256 KB
  float*  p    = (float*) (ws + 262144);     // 768 KB
  float*  Tf   = (float*) (ws + 5242880);    // 20 MB
  float*  wp   = (float*) (ws + 26214400);   // 640 KB
  float*  t1t  = (float*) (ws + 26869760);   // 48 KB
  float*  t2t  = (float*) (ws + 26918912);   // 256 KB
  float*  t3t  = (float*) (ws + 27181056);   // 256 KB
  float*  part = (float*) (ws + 33554432);   // 8 MB (SPLITK=4)
  float4* pts4 = (float4*)(ws + 52428800);   // 256 KB

  float* rep_pos = (float*)d_out;
  float* outp    = (float*)d_out + (size_t)GT*3;

  prep_kernel<<<640, 256, 0, stream>>>(t1_w, t2_w, t3_w, conv_w, points,
                                       t1t, t2t, t3t, wp, pts4);
  knn_kernel<<<GT/8, 512, 0, stream>>>(pts4, rep_idx, nb, p, rep_pos);
  mlp_tf_kernel<<<GT/MGB, 512, 0, stream>>>(p, t1t, t1_b, bn1_g, bn1_b,
                                            t2t, t2_b, bn2_g, bn2_b,
                                            t3t, t3_b, bn3_g, bn3_b,
                                            features, nb,
                                            lift_w, lift_b, bn_lift_g, bn_lift_b,
                                            Tf);
  dim3 ggrid(GT/32, SPLITK);
  gemm_kernel<<<ggrid, 256, 0, stream>>>(Tf, wp, part);
  reduce_kernel<<<(GT*COUT/4)/256, 256, 0, stream>>>(part, conv_b, outp);
}

// Round 11
// 199.655 us; speedup vs baseline: 1.2424x; 1.0299x over previous
//
#include <hip/hip_runtime.h>
#include <float.h>

#define Bn 2
#define Nn 8192
#define Rr 2048
#define Kk 16
#define CIN 64
#define CL 16
#define COUT 128
#define K2c 256
#define GT (Bn*Rr)      // 4096 groups
#define FD (CL+CIN)     // 80
#define KC (Kk*FD)      // 1280
#define MGB 8           // mlp groups per block (8 groups, 8 waves, 512 thr)
#define SPLITK 4        // gemm split-K
#define CCAP 128        // knn candidate cap; expected count ~53 (v5.1 statistic)

// ---------------- prep: weight transposes / permute + pts4 packing ----------------
__global__ __launch_bounds__(256) void prep_kernel(
    const float* __restrict__ t1_w, const float* __restrict__ t2_w,
    const float* __restrict__ t3_w, const float* __restrict__ conv_w,
    const float* __restrict__ points,
    float* __restrict__ t1t, float* __restrict__ t2t,
    float* __restrict__ t3t, float* __restrict__ wp,
    float4* __restrict__ pts4)
{
  int i = blockIdx.x * 256 + threadIdx.x;
  if (i < K2c*48) { int j = i / 48, k = i - j*48; t1t[k*K2c + j] = t1_w[i]; }
  if (i < K2c*K2c) { int j = i >> 8, k = i & 255; t2t[k*K2c + j] = t2_w[i]; t3t[k*K2c + j] = t3_w[i]; }
  if (i < COUT*KC) {
    int o = i / KC, ck = i - o*KC;
    int c = ck >> 4, k = ck & 15;
    wp[(k*FD + c)*COUT + o] = conv_w[i];
  }
  if (i < Bn*Nn) {
    float x = points[i*3+0], y = points[i*3+1], z = points[i*3+2];
    // numpy order: sq = (x*x + y*y) + z*z, muls materialized then summed
    float sq = __fadd_rn(__fadd_rn(__fmul_rn(x,x), __fmul_rn(y,y)), __fmul_rn(z,z));
    pts4[i] = make_float4(x, y, z, sq);
  }
}

// ---------------- knn v9 (unchanged, harness-verified): streamed points ----------------
// NOTE: (512,4) caps VGPR at 64 on this toolchain (2nd arg = min BLOCKS/CU,
// CUDA-style: 4 blk x 8 waves = 32 waves/CU -> 2048/32 = 64). knn fits in 64.
__global__ __launch_bounds__(512, 4) void knn_kernel(
    const float4* __restrict__ pts4, const int* __restrict__ rep_idx,
    int* __restrict__ nb_idx, float* __restrict__ p_out,
    float* __restrict__ rep_pos_out)
{
  __shared__ float cbuf[8][512];                 // 16 KB per-thread minima [q][t]
  __shared__ unsigned long long coll[8][CCAP];   // 8 KB candidates
  __shared__ float Lst[8][64];                   // 2 KB per-lane tau stats
  __shared__ float4 qS[8];
  __shared__ float  tauS[8];
  __shared__ int    ccnt[8];

  int t    = threadIdx.x;
  int lane = t & 63;
  int w    = t >> 6;                 // 0..7
  int g0   = blockIdx.x * 8;         // 8 | 2048: block never straddles batches
  int b    = g0 >> 11;
  const float4* pb4 = pts4 + (size_t)b*Nn;

  if (t < 8) {
    int g = g0 + t;
    int r = g & 2047;
    qS[t] = pb4[rep_idx[r]];
    ccnt[t] = 0;
  }
  __syncthreads();

  // queries to SGPRs (uniform across block)
  float qx[8], qy[8], qz[8], qw[8];
  #pragma unroll
  for (int q = 0; q < 8; q++) {
    float4 Q = qS[q];
    qx[q] = __uint_as_float(__builtin_amdgcn_readfirstlane(__float_as_uint(Q.x)));
    qy[q] = __uint_as_float(__builtin_amdgcn_readfirstlane(__float_as_uint(Q.y)));
    qz[q] = __uint_as_float(__builtin_amdgcn_readfirstlane(__float_as_uint(Q.z)));
    qw[q] = __uint_as_float(__builtin_amdgcn_readfirstlane(__float_as_uint(Q.w)));
  }

  // ---- pass 1: per-thread min d2 per query; points streamed 4-at-a-time ----
  float m[8];
  #pragma unroll
  for (int q = 0; q < 8; q++) m[q] = FLT_MAX;
  for (int i0 = 0; i0 < 16; i0 += 4) {
    float4 P0 = pb4[t + 512*(i0+0)];
    float4 P1 = pb4[t + 512*(i0+1)];
    float4 P2 = pb4[t + 512*(i0+2)];
    float4 P3 = pb4[t + 512*(i0+3)];
    #pragma unroll
    for (int q = 0; q < 8; q++) {
      float d0 = __fsub_rn(__fadd_rn(qw[q], P0.w), __fmul_rn(2.0f,
                 __fmaf_rn(qz[q], P0.z, __fmaf_rn(qy[q], P0.y, __fmul_rn(qx[q], P0.x)))));
      float d1 = __fsub_rn(__fadd_rn(qw[q], P1.w), __fmul_rn(2.0f,
                 __fmaf_rn(qz[q], P1.z, __fmaf_rn(qy[q], P1.y, __fmul_rn(qx[q], P1.x)))));
      float d2 = __fsub_rn(__fadd_rn(qw[q], P2.w), __fmul_rn(2.0f,
                 __fmaf_rn(qz[q], P2.z, __fmaf_rn(qy[q], P2.y, __fmul_rn(qx[q], P2.x)))));
      float d3 = __fsub_rn(__fadd_rn(qw[q], P3.w), __fmul_rn(2.0f,
                 __fmaf_rn(qz[q], P3.z, __fmaf_rn(qy[q], P3.y, __fmul_rn(qx[q], P3.x)))));
      m[q] = fminf(fminf(fminf(m[q], d0), fminf(d1, d2)), d3);
    }
  }

  #pragma unroll
  for (int q = 0; q < 8; q++) cbuf[q][t] = m[q];
  __syncthreads();

  // ---- tau: wave w handles query w ----
  {
    // per-lane 3rd-smallest of its 8 thread-minima (bounds 3 real distances)
    float C0 = FLT_MAX, C1 = FLT_MAX, C2 = FLT_MAX;
    #pragma unroll
    for (int j = 0; j < 8; j++) {
      float v = cbuf[w][lane + 64*j];
      float n2 = __builtin_amdgcn_fmed3f(C1, C2, v);
      float n1 = __builtin_amdgcn_fmed3f(C0, C1, v);
      float n0 = fminf(C0, v);
      C0 = n0; C1 = n1; C2 = n2;
    }
    Lst[w][lane] = C2;
  }
  __syncthreads();
  {
    // tau = 6th-smallest L (rank 5, lex (L,lane) unique) -> >=18 pts <= tau
    float L = Lst[w][lane];
    int rk = 0;
    #pragma unroll 8
    for (int i = 0; i < 64; i++) {
      float Li = Lst[w][i];
      rk += (Li < L || (Li == L && i < lane)) ? 1 : 0;
    }
    if (rk == 5) tauS[w] = L;
  }
  __syncthreads();

  float tau[8];
  #pragma unroll
  for (int q = 0; q < 8; q++)
    tau[q] = __uint_as_float(__builtin_amdgcn_readfirstlane(__float_as_uint(tauS[q])));

  // ---- pass 2: re-stream points (L2-hot), predicate + collect ----
  for (int i0 = 0; i0 < 16; i0 += 4) {
    float4 Pb[4];
    Pb[0] = pb4[t + 512*(i0+0)];
    Pb[1] = pb4[t + 512*(i0+1)];
    Pb[2] = pb4[t + 512*(i0+2)];
    Pb[3] = pb4[t + 512*(i0+3)];
    #pragma unroll
    for (int u = 0; u < 4; u++) {
      float4 P = Pb[u];
      int idx = t + 512*(i0+u);
      #pragma unroll
      for (int q = 0; q < 8; q++) {
        float dot = __fmaf_rn(qz[q], P.z, __fmaf_rn(qy[q], P.y, __fmul_rn(qx[q], P.x)));
        float d2  = __fsub_rn(__fadd_rn(qw[q], P.w), __fmul_rn(2.0f, dot));
        if (d2 <= tau[q]) {
          int pos = atomicAdd(&ccnt[q], 1);
          if (pos < CCAP) {
            unsigned f = __float_as_uint(d2);
            unsigned mono = f ^ ((unsigned)((int)f >> 31) | 0x80000000u);
            coll[q][pos] = ((unsigned long long)mono << 32) | (unsigned)idx;
          }
        }
      }
    }
  }
  __syncthreads();

  // ---- extraction: exact rank via broadcast-compare (no serial chains) ----
  int cnt = __builtin_amdgcn_readfirstlane(ccnt[w]);
  if (cnt > CCAP) cnt = CCAP;
  unsigned long long k1 = (lane < cnt)      ? coll[w][lane]      : ~0ull;
  unsigned long long k2 = (lane + 64 < cnt) ? coll[w][lane + 64] : ~0ull;
  int r1 = 0, r2 = 0;
  for (int i = 0; i < cnt; i++) {
    unsigned long long ki = coll[w][i];   // broadcast read
    r1 += (ki < k1) ? 1 : 0;
    r2 += (ki < k2) ? 1 : 0;
  }

  int g = g0 + w;
  float4 Q = qS[w];
  if (lane < cnt && r1 >= 1 && r1 <= 16) {
    int om = (int)(k1 & 0xFFFFFFFFull);
    nb_idx[g*Kk + r1 - 1] = om;
    float4 Pm = pb4[om];
    p_out[(g*Kk + r1 - 1)*3 + 0] = __fsub_rn(Pm.x, Q.x);
    p_out[(g*Kk + r1 - 1)*3 + 1] = __fsub_rn(Pm.y, Q.y);
    p_out[(g*Kk + r1 - 1)*3 + 2] = __fsub_rn(Pm.z, Q.z);
  }
  if (lane + 64 < cnt && r2 >= 1 && r2 <= 16) {
    int om = (int)(k2 & 0xFFFFFFFFull);
    nb_idx[g*Kk + r2 - 1] = om;
    float4 Pm = pb4[om];
    p_out[(g*Kk + r2 - 1)*3 + 0] = __fsub_rn(Pm.x, Q.x);
    p_out[(g*Kk + r2 - 1)*3 + 1] = __fsub_rn(Pm.y, Q.y);
    p_out[(g*Kk + r2 - 1)*3 + 2] = __fsub_rn(Pm.z, Q.z);
  }
  if (lane < 3) rep_pos_out[g*3 + lane] = (lane == 0 ? Q.x : (lane == 1 ? Q.y : Q.z));
}

// ---------------- mlp_tf v16: v13 revert + depth-6 prefetch (bounded tweak) ----------------
// v14/v15 post-mortem: single-phase reduce = MORE LDS ops/thread (64 vs 48)
// with 2x conflicts, and 78KB LDS killed the 3-blocks/CU capability
// (occupancy 34%->19%, dur 44->53). v16 reverts to v13's two-phase reduce +
// 33.8KB red + 44.5KB total LDS (3 blk/CU capable), changing ONLY the KLOOP
// prefetch depth 4->6 (stride 8, k+=48): distance ~280 VALU-cy covers the
// 200-300cy L2 latency; VGPR ~70 stays under 85 (= 2048/24, the limit that
// preserves 24-wave/CU capability; depth-8's ~88 would break it — part of
// v15's occupancy loss). Per-thread k-visit order unchanged (ascending,
// k === w mod 8) -> accumulation bit-identical to v13.
__device__ __forceinline__ void fma_g(float4& a, float hv, const float4& wv) {
  a.x = fmaf(hv, wv.x, a.x);
  a.y = fmaf(hv, wv.y, a.y);
  a.z = fmaf(hv, wv.z, a.z);
  a.w = fmaf(hv, wv.w, a.w);
}

__global__ __launch_bounds__(512) void mlp_tf_kernel(
    const float* __restrict__ p,
    const float* __restrict__ t1t, const float* __restrict__ t1_b,
    const float* __restrict__ g1v, const float* __restrict__ b1v,
    const float* __restrict__ t2t, const float* __restrict__ t2_b,
    const float* __restrict__ g2v, const float* __restrict__ b2v,
    const float* __restrict__ t3t, const float* __restrict__ t3_b,
    const float* __restrict__ g3v, const float* __restrict__ b3v,
    const float* __restrict__ features, const int* __restrict__ nb_idx,
    const float* __restrict__ lift_w, const float* __restrict__ lift_b,
    const float* __restrict__ bng, const float* __restrict__ bnb,
    float* __restrict__ Tf)
{
  __shared__ float pf[48][MGB];      // 1.5 KB (= p transposed; also serves tf lift)
  __shared__ float hA[K2c][MGB];     // 8 KB (layer I/O; reused as T_s after layer 3)
  __shared__ float red[128*66];      // 33.8 KB (two-phase reduction; f_s reuse in tf)
  __shared__ int   idxs[128];        // 512 B (8 groups x 16 neighbors)
  __shared__ float lw[48], lb2[16], lg[16], lo[16];
  int t = threadIdx.x;
  int w = t >> 6, l = t & 63;
  int g0 = blockIdx.x * MGB;
  int bb_ = g0 / Rr;                 // batch (8 | 2048: never straddles)
  for (int e = t; e < MGB*48; e += 512) {
    int g = e / 48, k = e - g*48;
    pf[k][g] = p[(size_t)(g0+g)*48 + k];
  }
  if (t < 128) idxs[t] = nb_idx[g0*16 + t];
  else if (t >= 128 && t < 176) lw[t-128]  = lift_w[t-128];
  else if (t >= 176 && t < 192) lb2[t-176] = lift_b[t-176];
  else if (t >= 192 && t < 208) lg[t-192]  = bng[t-192];
  else if (t >= 208 && t < 224) lo[t-208]  = bnb[t-208];
  __syncthreads();

  float4 acc[MGB];   // acc[q] = group q over cols 4l..4l+3
  int col = t & 255; // output neuron this thread reduces/writes
  int h   = t >> 8;  // group-half (0: q0..3, 1: q4..7)
  int cc  = col & 3, lr = col >> 2;

#define LDW(WSRC, K) (*(const float4*)&WSRC[(size_t)(K)*K2c + 4*l])

#define KSTAGE(WSRC, KDIM, HBUF, WB, KK, KNEXT)                        \
  {                                                                    \
    float4 wc = WB;                                                    \
    if ((KNEXT) < KDIM) WB = LDW(WSRC, KNEXT);                         \
    float4 ha = *(const float4*)&HBUF[KK][0];                          \
    float4 hb = *(const float4*)&HBUF[KK][4];                          \
    fma_g(acc[0], ha.x, wc); fma_g(acc[1], ha.y, wc);                  \
    fma_g(acc[2], ha.z, wc); fma_g(acc[3], ha.w, wc);                  \
    fma_g(acc[4], hb.x, wc); fma_g(acc[5], hb.y, wc);                  \
    fma_g(acc[6], hb.z, wc); fma_g(acc[7], hb.w, wc);                  \
  }

#define KLOOP(WSRC, KDIM, HBUF)                                        \
  {                                                                    \
    _Pragma("unroll")                                                  \
    for (int q = 0; q < MGB; q++) acc[q] = make_float4(0.f,0.f,0.f,0.f);\
    float4 wb0 = LDW(WSRC, w);                                         \
    float4 wb1 = (w + 8  < KDIM) ? LDW(WSRC, w + 8)  : wb0;            \
    float4 wb2 = (w + 16 < KDIM) ? LDW(WSRC, w + 16) : wb0;            \
    float4 wb3 = (w + 24 < KDIM) ? LDW(WSRC, w + 24) : wb0;            \
    float4 wb4 = (w + 32 < KDIM) ? LDW(WSRC, w + 32) : wb0;            \
    float4 wb5 = (w + 40 < KDIM) ? LDW(WSRC, w + 40) : wb0;            \
    for (int k = w; k < KDIM; k += 48) {                               \
      KSTAGE(WSRC, KDIM, HBUF, wb0, k,      k + 48)                    \
      if (k + 8  < KDIM) KSTAGE(WSRC, KDIM, HBUF, wb1, k + 8,  k + 56) \
      if (k + 16 < KDIM) KSTAGE(WSRC, KDIM, HBUF, wb2, k + 16, k + 64) \
      if (k + 24 < KDIM) KSTAGE(WSRC, KDIM, HBUF, wb3, k + 24, k + 72) \
      if (k + 32 < KDIM) KSTAGE(WSRC, KDIM, HBUF, wb4, k + 32, k + 80) \
      if (k + 40 < KDIM) KSTAGE(WSRC, KDIM, HBUF, wb5, k + 40, k + 88) \
    }                                                                  \
  }

// two-phase cross-wave reduce: waves 0-3 write rows, waves 4-7 accumulate
#define WRITE_RED()                                                    \
  {                                                                    \
    if (w < 4) {                                                       \
      _Pragma("unroll")                                                \
      for (int q = 0; q < MGB; q++) {                                  \
        red[((w*4 + 0)*8 + q)*66 + l] = acc[q].x;                      \
        red[((w*4 + 1)*8 + q)*66 + l] = acc[q].y;                      \
        red[((w*4 + 2)*8 + q)*66 + l] = acc[q].z;                      \
        red[((w*4 + 3)*8 + q)*66 + l] = acc[q].w;                      \
      }                                                                \
    }                                                                  \
    __syncthreads();                                                   \
    if (w >= 4) {                                                      \
      int w2 = w - 4;                                                  \
      _Pragma("unroll")                                                \
      for (int q = 0; q < MGB; q++) {                                  \
        red[((w2*4 + 0)*8 + q)*66 + l] += acc[q].x;                    \
        red[((w2*4 + 1)*8 + q)*66 + l] += acc[q].y;                    \
        red[((w2*4 + 2)*8 + q)*66 + l] += acc[q].z;                    \
        red[((w2*4 + 3)*8 + q)*66 + l] += acc[q].w;                    \
      }                                                                \
    }                                                                  \
    __syncthreads();                                                   \
  }

// thread t sums 4 ww-rows for its (col, group-half): S[qi] = out[col, h*4+qi]
#define REDUCE(S)                                                      \
  float S[4] = {0.f, 0.f, 0.f, 0.f};                                   \
  {                                                                    \
    _Pragma("unroll")                                                  \
    for (int ww = 0; ww < 4; ww++) {                                   \
      _Pragma("unroll")                                                \
      for (int qi = 0; qi < 4; qi++)                                   \
        S[qi] += red[((ww*4 + cc)*8 + (h*4 + qi))*66 + lr];            \
    }                                                                  \
  }

  // ===== layer 1 (K=48), relu =====
  KLOOP(t1t, 48, pf)
  WRITE_RED()
  {
    REDUCE(s)
    float bb = t1_b[col], gg = g1v[col], oo = b1v[col];
    float4 v;
    v.x = fmaxf(fmaf(s[0] + bb, gg, oo), 0.f);
    v.y = fmaxf(fmaf(s[1] + bb, gg, oo), 0.f);
    v.z = fmaxf(fmaf(s[2] + bb, gg, oo), 0.f);
    v.w = fmaxf(fmaf(s[3] + bb, gg, oo), 0.f);
    *(float4*)&hA[col][h*4] = v;
  }
  __syncthreads();

  // ===== layer 2 (K=256), relu =====
  KLOOP(t2t, K2c, hA)
  WRITE_RED()
  {
    REDUCE(s)
    float bb = t2_b[col], gg = g2v[col], oo = b2v[col];
    float4 v;
    v.x = fmaxf(fmaf(s[0] + bb, gg, oo), 0.f);
    v.y = fmaxf(fmaf(s[1] + bb, gg, oo), 0.f);
    v.z = fmaxf(fmaf(s[2] + bb, gg, oo), 0.f);
    v.w = fmaxf(fmaf(s[3] + bb, gg, oo), 0.f);
    *(float4*)&hA[col][h*4] = v;
  }
  __syncthreads();

  // ===== layer 3 (K=256), no relu, T -> LDS (hA reused as T_s) =====
  KLOOP(t3t, K2c, hA)
  WRITE_RED()
  float* T_s = &hA[0][0];   // T_s[g*256 + col]; hA dead after last KLOOP
  {
    REDUCE(s)
    float bb = t3_b[col], gg = g3v[col], oo = b3v[col];
    #pragma unroll
    for (int qi = 0; qi < 4; qi++)
      T_s[(h*4 + qi)*K2c + col] = fmaf(s[qi] + bb, gg, oo);
  }
  __syncthreads();          // red reads done (f_s reuse safe), T_s visible

  // ===== tf phase: 4 groups per pass, 2 passes (f_s reuses red) =====
  float* f_s = red;         // f_s[gg4*KC + k*FD + c], 4*1280 floats = 20 KB
  for (int pass = 0; pass < 2; pass++) {
    // gather neighbor features: 64 rows (4 groups x 16 nbrs) x 64 ch
    for (int row = w; row < 64; row += 8) {
      int gg4 = row >> 4, k = row & 15;
      int gl = pass*4 + gg4;
      f_s[gg4*KC + k*FD + CL + l] =
          features[((size_t)bb_*Nn + idxs[gl*16 + k])*CIN + l];
    }
    // lifted BN+ReLU: 4*16*16 = 1024 elements
    for (int e = t; e < 1024; e += 512) {
      int gg4 = e >> 8, rem = e & 255, k = rem >> 4, c = rem & 15;
      int gl = pass*4 + gg4;
      float a = pf[k*3 + 0][gl]*lw[c*3+0] + pf[k*3 + 1][gl]*lw[c*3+1]
              + pf[k*3 + 2][gl]*lw[c*3+2] + lb2[c];
      a = a*lg[c] + lo[c];
      f_s[gg4*KC + k*FD + c] = fmaxf(a, 0.f);
    }
    __syncthreads();
    // T x feat: 2 waves per group (ci = sub*64 + lane)
    {
      int gg4 = w >> 1, sub = w & 1;
      int ci = sub*64 + l;
      if (ci < FD) {
        int gl = pass*4 + gg4;
        float fcol[16];
        #pragma unroll
        for (int j = 0; j < 16; j++) fcol[j] = f_s[gg4*KC + j*FD + ci];
        #pragma unroll
        for (int k = 0; k < 16; k++) {
          float a = 0.f;
          #pragma unroll
          for (int j = 0; j < 16; j++)
            a = fmaf(T_s[gl*K2c + k*16 + j], fcol[j], a);
          Tf[(size_t)(g0+gl)*KC + k*FD + ci] = a;
        }
      }
    }
    __syncthreads();        // f_s reads done before next pass overwrite
  }
#undef KLOOP
#undef KSTAGE
#undef LDW
#undef WRITE_RED
#undef REDUCE
}

// ---------------- gemm: out = Tf(4096x1280) @ Wp(1280x128), split-K=4 ----------------
__global__ __launch_bounds__(256) void gemm_kernel(
    const float* __restrict__ A,    // Tf
    const float* __restrict__ Bm,   // Wp
    float* __restrict__ part)       // [SPLITK][GT][COUT]
{
  __shared__ float As[16*36];
  __shared__ float Bs[16*COUT];
  int t = threadIdx.x;
  int m0 = blockIdx.x * 32;
  int ky = blockIdx.y;
  int kbase0 = ky * (KC/SPLITK);    // 320
  float acc[4][4];
  #pragma unroll
  for (int i = 0; i < 4; i++)
    #pragma unroll
    for (int j = 0; j < 4; j++) acc[i][j] = 0.f;
  int tn = t & 31, tm = t >> 5;

  for (int kt = 0; kt < KC/SPLITK; kt += 16) {
    int kb = kbase0 + kt;
    {
      int kcol = t & 15, row = t >> 4;
      As[kcol*36 + row]      = A[(size_t)(m0+row)*KC + kb + kcol];
      As[kcol*36 + row + 16] = A[(size_t)(m0+row+16)*KC + kb + kcol];
    }
    {
      int o = t & 127, kk2 = t >> 7;
      #pragma unroll
      for (int p4 = 0; p4 < 8; p4++) {
        int kk = kk2 + p4*2;
        Bs[kk*COUT + o] = Bm[(size_t)(kb+kk)*COUT + o];
      }
    }
    __syncthreads();
    #pragma unroll
    for (int kk = 0; kk < 16; kk++) {
      float4 a4 = *(const float4*)&As[kk*36 + tm*4];
      float4 b4 = *(const float4*)&Bs[kk*COUT + tn*4];
      float av[4] = {a4.x, a4.y, a4.z, a4.w};
      float bv[4] = {b4.x, b4.y, b4.z, b4.w};
      #pragma unroll
      for (int i = 0; i < 4; i++)
        #pragma unroll
        for (int j = 0; j < 4; j++) acc[i][j] = fmaf(av[i], bv[j], acc[i][j]);
    }
    __syncthreads();
  }
  #pragma unroll
  for (int i = 0; i < 4; i++) {
    float4 v = make_float4(acc[i][0], acc[i][1], acc[i][2], acc[i][3]);
    *(float4*)&part[((size_t)ky*GT + m0 + tm*4 + i)*COUT + tn*4] = v;
  }
}

// ---------------- reduce: out = sum(part[0..SPLITK-1]) + bias ----------------
__global__ __launch_bounds__(256) void reduce_kernel(
    const float* __restrict__ part, const float* __restrict__ conv_b,
    float* __restrict__ outp)
{
  int i = blockIdx.x*256 + threadIdx.x;
  float4 s = ((const float4*)conv_b)[i & 31];
  #pragma unroll
  for (int w = 0; w < SPLITK; w++) {
    float4 v = ((const float4*)(part + (size_t)w*GT*COUT))[i];
    s.x += v.x; s.y += v.y; s.z += v.z; s.w += v.w;
  }
  ((float4*)outp)[i] = s;
}

extern "C" void kernel_launch(void* const* d_in, const int* in_sizes, int n_in,
                              void* d_out, int out_size, void* d_ws, size_t ws_size,
                              hipStream_t stream) {
  const float* points   = (const float*)d_in[0];
  const float* features = (const float*)d_in[1];
  const float* lift_w   = (const float*)d_in[2];
  const float* lift_b   = (const float*)d_in[3];
  const float* bn_lift_g= (const float*)d_in[4];
  const float* bn_lift_b= (const float*)d_in[5];
  const float* t1_w     = (const float*)d_in[6];
  const float* t1_b     = (const float*)d_in[7];
  const float* bn1_g    = (const float*)d_in[8];
  const float* bn1_b    = (const float*)d_in[9];
  const float* t2_w     = (const float*)d_in[10];
  const float* t2_b     = (const float*)d_in[11];
  const float* bn2_g    = (const float*)d_in[12];
  const float* bn2_b    = (const float*)d_in[13];
  const float* t3_w     = (const float*)d_in[14];
  const float* t3_b     = (const float*)d_in[15];
  const float* bn3_g    = (const float*)d_in[16];
  const float* bn3_b    = (const float*)d_in[17];
  const float* conv_w   = (const float*)d_in[18];
  const float* conv_b   = (const float*)d_in[19];
  const int*   rep_idx  = (const int*)d_in[20];

  char* ws = (char*)d_ws;
  int*    nb   = (int*)   (ws + 0);          // 256 KB
  float*  p    = (float*) (ws + 262144);     // 768 KB
  float*  Tf   = (float*) (ws + 5242880);    // 20 MB
  float*  wp   = (float*) (ws + 26214400);   // 640 KB
  float*  t1t  = (float*) (ws + 26869760);   // 48 KB
  float*  t2t  = (float*) (ws + 26918912);   // 256 KB
  float*  t3t  = (float*) (ws + 27181056);   // 256 KB
  float*  part = (float*) (ws + 33554432);   // 8 MB (SPLITK=4)
  float4* pts4 = (float4*)(ws + 52428800);   // 256 KB

  float* rep_pos = (float*)d_out;
  float* outp    = (float*)d_out + (size_t)GT*3;

  prep_kernel<<<640, 256, 0, stream>>>(t1_w, t2_w, t3_w, conv_w, points,
                                       t1t, t2t, t3t, wp, pts4);
  knn_kernel<<<GT/8, 512, 0, stream>>>(pts4, rep_idx, nb, p, rep_pos);
  mlp_tf_kernel<<<GT/MGB, 512, 0, stream>>>(p, t1t, t1_b, bn1_g, bn1_b,
                                            t2t, t2_b, bn2_g, bn2_b,
                                            t3t, t3_b, bn3_g, bn3_b,
                                            features, nb,
                                            lift_w, lift_b, bn_lift_g, bn_lift_b,
                                            Tf);
  dim3 ggrid(GT/32, SPLITK);
  gemm_kernel<<<ggrid, 256, 0, stream>>>(Tf, wp, part);
  reduce_kernel<<<(GT*COUT/4)/256, 256, 0, stream>>>(part, conv_b, outp);
}

// Round 12
// 190.637 us; speedup vs baseline: 1.3011x; 1.0473x over previous
//
#include <hip/hip_runtime.h>
#include <float.h>

#define Bn 2
#define Nn 8192
#define Rr 2048
#define Kk 16
#define CIN 64
#define CL 16
#define COUT 128
#define K2c 256
#define GT (Bn*Rr)      // 4096 groups
#define FD (CL+CIN)     // 80
#define KC (Kk*FD)      // 1280
#define MGB 8           // mlp groups per block (8 groups, 8 waves, 512 thr)
#define SPLITK 4        // gemm split-K
#define CCAP 128        // knn candidate cap; expected count ~53 (v5.1 statistic)

// ---------------- prep: weight transposes / permute + pts4 packing ----------------
__global__ __launch_bounds__(256) void prep_kernel(
    const float* __restrict__ t1_w, const float* __restrict__ t2_w,
    const float* __restrict__ t3_w, const float* __restrict__ conv_w,
    const float* __restrict__ points,
    float* __restrict__ t1t, float* __restrict__ t2t,
    float* __restrict__ t3t, float* __restrict__ wp,
    float4* __restrict__ pts4)
{
  int i = blockIdx.x * 256 + threadIdx.x;
  if (i < K2c*48) { int j = i / 48, k = i - j*48; t1t[k*K2c + j] = t1_w[i]; }
  if (i < K2c*K2c) { int j = i >> 8, k = i & 255; t2t[k*K2c + j] = t2_w[i]; t3t[k*K2c + j] = t3_w[i]; }
  if (i < COUT*KC) {
    int o = i / KC, ck = i - o*KC;
    int c = ck >> 4, k = ck & 15;
    wp[(k*FD + c)*COUT + o] = conv_w[i];
  }
  if (i < Bn*Nn) {
    float x = points[i*3+0], y = points[i*3+1], z = points[i*3+2];
    // numpy order: sq = (x*x + y*y) + z*z, muls materialized then summed
    float sq = __fadd_rn(__fadd_rn(__fmul_rn(x,x), __fmul_rn(y,y)), __fmul_rn(z,z));
    pts4[i] = make_float4(x, y, z, sq);
  }
}

// ---------------- knn v9 (unchanged, harness-verified): streamed points ----------------
// NOTE: (512,4) caps VGPR at 64 on this toolchain (2nd arg = min BLOCKS/CU,
// CUDA-style: 4 blk x 8 waves = 32 waves/CU -> 2048/32 = 64). knn fits in 64.
__global__ __launch_bounds__(512, 4) void knn_kernel(
    const float4* __restrict__ pts4, const int* __restrict__ rep_idx,
    int* __restrict__ nb_idx, float* __restrict__ p_out,
    float* __restrict__ rep_pos_out)
{
  __shared__ float cbuf[8][512];                 // 16 KB per-thread minima [q][t]
  __shared__ unsigned long long coll[8][CCAP];   // 8 KB candidates
  __shared__ float Lst[8][64];                   // 2 KB per-lane tau stats
  __shared__ float4 qS[8];
  __shared__ float  tauS[8];
  __shared__ int    ccnt[8];

  int t    = threadIdx.x;
  int lane = t & 63;
  int w    = t >> 6;                 // 0..7
  int g0   = blockIdx.x * 8;         // 8 | 2048: block never straddles batches
  int b    = g0 >> 11;
  const float4* pb4 = pts4 + (size_t)b*Nn;

  if (t < 8) {
    int g = g0 + t;
    int r = g & 2047;
    qS[t] = pb4[rep_idx[r]];
    ccnt[t] = 0;
  }
  __syncthreads();

  // queries to SGPRs (uniform across block)
  float qx[8], qy[8], qz[8], qw[8];
  #pragma unroll
  for (int q = 0; q < 8; q++) {
    float4 Q = qS[q];
    qx[q] = __uint_as_float(__builtin_amdgcn_readfirstlane(__float_as_uint(Q.x)));
    qy[q] = __uint_as_float(__builtin_amdgcn_readfirstlane(__float_as_uint(Q.y)));
    qz[q] = __uint_as_float(__builtin_amdgcn_readfirstlane(__float_as_uint(Q.z)));
    qw[q] = __uint_as_float(__builtin_amdgcn_readfirstlane(__float_as_uint(Q.w)));
  }

  // ---- pass 1: per-thread min d2 per query; points streamed 4-at-a-time ----
  float m[8];
  #pragma unroll
  for (int q = 0; q < 8; q++) m[q] = FLT_MAX;
  for (int i0 = 0; i0 < 16; i0 += 4) {
    float4 P0 = pb4[t + 512*(i0+0)];
    float4 P1 = pb4[t + 512*(i0+1)];
    float4 P2 = pb4[t + 512*(i0+2)];
    float4 P3 = pb4[t + 512*(i0+3)];
    #pragma unroll
    for (int q = 0; q < 8; q++) {
      float d0 = __fsub_rn(__fadd_rn(qw[q], P0.w), __fmul_rn(2.0f,
                 __fmaf_rn(qz[q], P0.z, __fmaf_rn(qy[q], P0.y, __fmul_rn(qx[q], P0.x)))));
      float d1 = __fsub_rn(__fadd_rn(qw[q], P1.w), __fmul_rn(2.0f,
                 __fmaf_rn(qz[q], P1.z, __fmaf_rn(qy[q], P1.y, __fmul_rn(qx[q], P1.x)))));
      float d2 = __fsub_rn(__fadd_rn(qw[q], P2.w), __fmul_rn(2.0f,
                 __fmaf_rn(qz[q], P2.z, __fmaf_rn(qy[q], P2.y, __fmul_rn(qx[q], P2.x)))));
      float d3 = __fsub_rn(__fadd_rn(qw[q], P3.w), __fmul_rn(2.0f,
                 __fmaf_rn(qz[q], P3.z, __fmaf_rn(qy[q], P3.y, __fmul_rn(qx[q], P3.x)))));
      m[q] = fminf(fminf(fminf(m[q], d0), fminf(d1, d2)), d3);
    }
  }

  #pragma unroll
  for (int q = 0; q < 8; q++) cbuf[q][t] = m[q];
  __syncthreads();

  // ---- tau: wave w handles query w ----
  {
    // per-lane 3rd-smallest of its 8 thread-minima (bounds 3 real distances)
    float C0 = FLT_MAX, C1 = FLT_MAX, C2 = FLT_MAX;
    #pragma unroll
    for (int j = 0; j < 8; j++) {
      float v = cbuf[w][lane + 64*j];
      float n2 = __builtin_amdgcn_fmed3f(C1, C2, v);
      float n1 = __builtin_amdgcn_fmed3f(C0, C1, v);
      float n0 = fminf(C0, v);
      C0 = n0; C1 = n1; C2 = n2;
    }
    Lst[w][lane] = C2;
  }
  __syncthreads();
  {
    // tau = 6th-smallest L (rank 5, lex (L,lane) unique) -> >=18 pts <= tau
    float L = Lst[w][lane];
    int rk = 0;
    #pragma unroll 8
    for (int i = 0; i < 64; i++) {
      float Li = Lst[w][i];
      rk += (Li < L || (Li == L && i < lane)) ? 1 : 0;
    }
    if (rk == 5) tauS[w] = L;
  }
  __syncthreads();

  float tau[8];
  #pragma unroll
  for (int q = 0; q < 8; q++)
    tau[q] = __uint_as_float(__builtin_amdgcn_readfirstlane(__float_as_uint(tauS[q])));

  // ---- pass 2: re-stream points (L2-hot), predicate + collect ----
  for (int i0 = 0; i0 < 16; i0 += 4) {
    float4 Pb[4];
    Pb[0] = pb4[t + 512*(i0+0)];
    Pb[1] = pb4[t + 512*(i0+1)];
    Pb[2] = pb4[t + 512*(i0+2)];
    Pb[3] = pb4[t + 512*(i0+3)];
    #pragma unroll
    for (int u = 0; u < 4; u++) {
      float4 P = Pb[u];
      int idx = t + 512*(i0+u);
      #pragma unroll
      for (int q = 0; q < 8; q++) {
        float dot = __fmaf_rn(qz[q], P.z, __fmaf_rn(qy[q], P.y, __fmul_rn(qx[q], P.x)));
        float d2  = __fsub_rn(__fadd_rn(qw[q], P.w), __fmul_rn(2.0f, dot));
        if (d2 <= tau[q]) {
          int pos = atomicAdd(&ccnt[q], 1);
          if (pos < CCAP) {
            unsigned f = __float_as_uint(d2);
            unsigned mono = f ^ ((unsigned)((int)f >> 31) | 0x80000000u);
            coll[q][pos] = ((unsigned long long)mono << 32) | (unsigned)idx;
          }
        }
      }
    }
  }
  __syncthreads();

  // ---- extraction: exact rank via broadcast-compare (no serial chains) ----
  int cnt = __builtin_amdgcn_readfirstlane(ccnt[w]);
  if (cnt > CCAP) cnt = CCAP;
  unsigned long long k1 = (lane < cnt)      ? coll[w][lane]      : ~0ull;
  unsigned long long k2 = (lane + 64 < cnt) ? coll[w][lane + 64] : ~0ull;
  int r1 = 0, r2 = 0;
  for (int i = 0; i < cnt; i++) {
    unsigned long long ki = coll[w][i];   // broadcast read
    r1 += (ki < k1) ? 1 : 0;
    r2 += (ki < k2) ? 1 : 0;
  }

  int g = g0 + w;
  float4 Q = qS[w];
  if (lane < cnt && r1 >= 1 && r1 <= 16) {
    int om = (int)(k1 & 0xFFFFFFFFull);
    nb_idx[g*Kk + r1 - 1] = om;
    float4 Pm = pb4[om];
    p_out[(g*Kk + r1 - 1)*3 + 0] = __fsub_rn(Pm.x, Q.x);
    p_out[(g*Kk + r1 - 1)*3 + 1] = __fsub_rn(Pm.y, Q.y);
    p_out[(g*Kk + r1 - 1)*3 + 2] = __fsub_rn(Pm.z, Q.z);
  }
  if (lane + 64 < cnt && r2 >= 1 && r2 <= 16) {
    int om = (int)(k2 & 0xFFFFFFFFull);
    nb_idx[g*Kk + r2 - 1] = om;
    float4 Pm = pb4[om];
    p_out[(g*Kk + r2 - 1)*3 + 0] = __fsub_rn(Pm.x, Q.x);
    p_out[(g*Kk + r2 - 1)*3 + 1] = __fsub_rn(Pm.y, Q.y);
    p_out[(g*Kk + r2 - 1)*3 + 2] = __fsub_rn(Pm.z, Q.z);
  }
  if (lane < 3) rep_pos_out[g*3 + lane] = (lane == 0 ? Q.x : (lane == 1 ? Q.y : Q.z));
}

// ---------------- mlp_tf v17 = v13 (verified best: 44us, total 192.7) ----------------
// v14-v16 post-mortems mapped the VGPR cliff: waves/SIMD halves 8->4 at
// VGPR>64. v13's depth-4 prefetch = 56 VGPR sits under the cliff (occ 34%);
// depth-6 (68) and depth-8 (88) both crossed it (occ 19%) and lost 8-9us.
// v13 is the optimum against the cliff; restored verbatim. LDS 44.5KB,
// two-phase reduce, no launch-bounds cap.
__device__ __forceinline__ void fma_g(float4& a, float hv, const float4& wv) {
  a.x = fmaf(hv, wv.x, a.x);
  a.y = fmaf(hv, wv.y, a.y);
  a.z = fmaf(hv, wv.z, a.z);
  a.w = fmaf(hv, wv.w, a.w);
}

__global__ __launch_bounds__(512) void mlp_tf_kernel(
    const float* __restrict__ p,
    const float* __restrict__ t1t, const float* __restrict__ t1_b,
    const float* __restrict__ g1v, const float* __restrict__ b1v,
    const float* __restrict__ t2t, const float* __restrict__ t2_b,
    const float* __restrict__ g2v, const float* __restrict__ b2v,
    const float* __restrict__ t3t, const float* __restrict__ t3_b,
    const float* __restrict__ g3v, const float* __restrict__ b3v,
    const float* __restrict__ features, const int* __restrict__ nb_idx,
    const float* __restrict__ lift_w, const float* __restrict__ lift_b,
    const float* __restrict__ bng, const float* __restrict__ bnb,
    float* __restrict__ Tf)
{
  __shared__ float pf[48][MGB];      // 1.5 KB (= p transposed; also serves tf lift)
  __shared__ float hA[K2c][MGB];     // 8 KB (layer I/O; reused as T_s after layer 3)
  __shared__ float red[128*66];      // 33.8 KB (two-phase reduction; f_s reuse in tf)
  __shared__ int   idxs[128];        // 512 B (8 groups x 16 neighbors)
  __shared__ float lw[48], lb2[16], lg[16], lo[16];
  int t = threadIdx.x;
  int w = t >> 6, l = t & 63;
  int g0 = blockIdx.x * MGB;
  int bb_ = g0 / Rr;                 // batch (8 | 2048: never straddles)
  for (int e = t; e < MGB*48; e += 512) {
    int g = e / 48, k = e - g*48;
    pf[k][g] = p[(size_t)(g0+g)*48 + k];
  }
  if (t < 128) idxs[t] = nb_idx[g0*16 + t];
  else if (t >= 128 && t < 176) lw[t-128]  = lift_w[t-128];
  else if (t >= 176 && t < 192) lb2[t-176] = lift_b[t-176];
  else if (t >= 192 && t < 208) lg[t-192]  = bng[t-192];
  else if (t >= 208 && t < 224) lo[t-208]  = bnb[t-208];
  __syncthreads();

  float4 acc[MGB];   // acc[q] = group q over cols 4l..4l+3
  int col = t & 255; // output neuron this thread reduces/writes
  int h   = t >> 8;  // group-half (0: q0..3, 1: q4..7)
  int cc  = col & 3, lr = col >> 2;

#define LDW(WSRC, K) (*(const float4*)&WSRC[(size_t)(K)*K2c + 4*l])

#define KSTAGE(WSRC, KDIM, HBUF, WB, KK, KNEXT)                        \
  {                                                                    \
    float4 wc = WB;                                                    \
    if ((KNEXT) < KDIM) WB = LDW(WSRC, KNEXT);                         \
    float4 ha = *(const float4*)&HBUF[KK][0];                          \
    float4 hb = *(const float4*)&HBUF[KK][4];                          \
    fma_g(acc[0], ha.x, wc); fma_g(acc[1], ha.y, wc);                  \
    fma_g(acc[2], ha.z, wc); fma_g(acc[3], ha.w, wc);                  \
    fma_g(acc[4], hb.x, wc); fma_g(acc[5], hb.y, wc);                  \
    fma_g(acc[6], hb.z, wc); fma_g(acc[7], hb.w, wc);                  \
  }

#define KLOOP(WSRC, KDIM, HBUF)                                        \
  {                                                                    \
    _Pragma("unroll")                                                  \
    for (int q = 0; q < MGB; q++) acc[q] = make_float4(0.f,0.f,0.f,0.f);\
    float4 wb0 = LDW(WSRC, w);                                         \
    float4 wb1 = (w + 8  < KDIM) ? LDW(WSRC, w + 8)  : wb0;            \
    float4 wb2 = (w + 16 < KDIM) ? LDW(WSRC, w + 16) : wb0;            \
    float4 wb3 = (w + 24 < KDIM) ? LDW(WSRC, w + 24) : wb0;            \
    for (int k = w; k < KDIM; k += 32) {                               \
      KSTAGE(WSRC, KDIM, HBUF, wb0, k,      k + 32)                    \
      if (k + 8  < KDIM) KSTAGE(WSRC, KDIM, HBUF, wb1, k + 8,  k + 40) \
      if (k + 16 < KDIM) KSTAGE(WSRC, KDIM, HBUF, wb2, k + 16, k + 48) \
      if (k + 24 < KDIM) KSTAGE(WSRC, KDIM, HBUF, wb3, k + 24, k + 56) \
    }                                                                  \
  }

// two-phase cross-wave reduce: waves 0-3 write rows, waves 4-7 accumulate
#define WRITE_RED()                                                    \
  {                                                                    \
    if (w < 4) {                                                       \
      _Pragma("unroll")                                                \
      for (int q = 0; q < MGB; q++) {                                  \
        red[((w*4 + 0)*8 + q)*66 + l] = acc[q].x;                      \
        red[((w*4 + 1)*8 + q)*66 + l] = acc[q].y;                      \
        red[((w*4 + 2)*8 + q)*66 + l] = acc[q].z;                      \
        red[((w*4 + 3)*8 + q)*66 + l] = acc[q].w;                      \
      }                                                                \
    }                                                                  \
    __syncthreads();                                                   \
    if (w >= 4) {                                                      \
      int w2 = w - 4;                                                  \
      _Pragma("unroll")                                                \
      for (int q = 0; q < MGB; q++) {                                  \
        red[((w2*4 + 0)*8 + q)*66 + l] += acc[q].x;                    \
        red[((w2*4 + 1)*8 + q)*66 + l] += acc[q].y;                    \
        red[((w2*4 + 2)*8 + q)*66 + l] += acc[q].z;                    \
        red[((w2*4 + 3)*8 + q)*66 + l] += acc[q].w;                    \
      }                                                                \
    }                                                                  \
    __syncthreads();                                                   \
  }

// thread t sums 4 ww-rows for its (col, group-half): S[qi] = out[col, h*4+qi]
#define REDUCE(S)                                                      \
  float S[4] = {0.f, 0.f, 0.f, 0.f};                                   \
  {                                                                    \
    _Pragma("unroll")                                                  \
    for (int ww = 0; ww < 4; ww++) {                                   \
      _Pragma("unroll")                                                \
      for (int qi = 0; qi < 4; qi++)                                   \
        S[qi] += red[((ww*4 + cc)*8 + (h*4 + qi))*66 + lr];            \
    }                                                                  \
  }

  // ===== layer 1 (K=48), relu =====
  KLOOP(t1t, 48, pf)
  WRITE_RED()
  {
    REDUCE(s)
    float bb = t1_b[col], gg = g1v[col], oo = b1v[col];
    float4 v;
    v.x = fmaxf(fmaf(s[0] + bb, gg, oo), 0.f);
    v.y = fmaxf(fmaf(s[1] + bb, gg, oo), 0.f);
    v.z = fmaxf(fmaf(s[2] + bb, gg, oo), 0.f);
    v.w = fmaxf(fmaf(s[3] + bb, gg, oo), 0.f);
    *(float4*)&hA[col][h*4] = v;
  }
  __syncthreads();

  // ===== layer 2 (K=256), relu =====
  KLOOP(t2t, K2c, hA)
  WRITE_RED()
  {
    REDUCE(s)
    float bb = t2_b[col], gg = g2v[col], oo = b2v[col];
    float4 v;
    v.x = fmaxf(fmaf(s[0] + bb, gg, oo), 0.f);
    v.y = fmaxf(fmaf(s[1] + bb, gg, oo), 0.f);
    v.z = fmaxf(fmaf(s[2] + bb, gg, oo), 0.f);
    v.w = fmaxf(fmaf(s[3] + bb, gg, oo), 0.f);
    *(float4*)&hA[col][h*4] = v;
  }
  __syncthreads();

  // ===== layer 3 (K=256), no relu, T -> LDS (hA reused as T_s) =====
  KLOOP(t3t, K2c, hA)
  WRITE_RED()
  float* T_s = &hA[0][0];   // T_s[g*256 + col]; hA dead after last KLOOP
  {
    REDUCE(s)
    float bb = t3_b[col], gg = g3v[col], oo = b3v[col];
    #pragma unroll
    for (int qi = 0; qi < 4; qi++)
      T_s[(h*4 + qi)*K2c + col] = fmaf(s[qi] + bb, gg, oo);
  }
  __syncthreads();          // red reads done (f_s reuse safe), T_s visible

  // ===== tf phase: 4 groups per pass, 2 passes (f_s reuses red) =====
  float* f_s = red;         // f_s[gg4*KC + k*FD + c], 4*1280 floats = 20 KB
  for (int pass = 0; pass < 2; pass++) {
    // gather neighbor features: 64 rows (4 groups x 16 nbrs) x 64 ch
    for (int row = w; row < 64; row += 8) {
      int gg4 = row >> 4, k = row & 15;
      int gl = pass*4 + gg4;
      f_s[gg4*KC + k*FD + CL + l] =
          features[((size_t)bb_*Nn + idxs[gl*16 + k])*CIN + l];
    }
    // lifted BN+ReLU: 4*16*16 = 1024 elements
    for (int e = t; e < 1024; e += 512) {
      int gg4 = e >> 8, rem = e & 255, k = rem >> 4, c = rem & 15;
      int gl = pass*4 + gg4;
      float a = pf[k*3 + 0][gl]*lw[c*3+0] + pf[k*3 + 1][gl]*lw[c*3+1]
              + pf[k*3 + 2][gl]*lw[c*3+2] + lb2[c];
      a = a*lg[c] + lo[c];
      f_s[gg4*KC + k*FD + c] = fmaxf(a, 0.f);
    }
    __syncthreads();
    // T x feat: 2 waves per group (ci = sub*64 + lane)
    {
      int gg4 = w >> 1, sub = w & 1;
      int ci = sub*64 + l;
      if (ci < FD) {
        int gl = pass*4 + gg4;
        float fcol[16];
        #pragma unroll
        for (int j = 0; j < 16; j++) fcol[j] = f_s[gg4*KC + j*FD + ci];
        #pragma unroll
        for (int k = 0; k < 16; k++) {
          float a = 0.f;
          #pragma unroll
          for (int j = 0; j < 16; j++)
            a = fmaf(T_s[gl*K2c + k*16 + j], fcol[j], a);
          Tf[(size_t)(g0+gl)*KC + k*FD + ci] = a;
        }
      }
    }
    __syncthreads();        // f_s reads done before next pass overwrite
  }
#undef KLOOP
#undef KSTAGE
#undef LDW
#undef WRITE_RED
#undef REDUCE
}

// ---------------- gemm: out = Tf(4096x1280) @ Wp(1280x128), split-K=4 ----------------
__global__ __launch_bounds__(256) void gemm_kernel(
    const float* __restrict__ A,    // Tf
    const float* __restrict__ Bm,   // Wp
    float* __restrict__ part)       // [SPLITK][GT][COUT]
{
  __shared__ float As[16*36];
  __shared__ float Bs[16*COUT];
  int t = threadIdx.x;
  int m0 = blockIdx.x * 32;
  int ky = blockIdx.y;
  int kbase0 = ky * (KC/SPLITK);    // 320
  float acc[4][4];
  #pragma unroll
  for (int i = 0; i < 4; i++)
    #pragma unroll
    for (int j = 0; j < 4; j++) acc[i][j] = 0.f;
  int tn = t & 31, tm = t >> 5;

  for (int kt = 0; kt < KC/SPLITK; kt += 16) {
    int kb = kbase0 + kt;
    {
      int kcol = t & 15, row = t >> 4;
      As[kcol*36 + row]      = A[(size_t)(m0+row)*KC + kb + kcol];
      As[kcol*36 + row + 16] = A[(size_t)(m0+row+16)*KC + kb + kcol];
    }
    {
      int o = t & 127, kk2 = t >> 7;
      #pragma unroll
      for (int p4 = 0; p4 < 8; p4++) {
        int kk = kk2 + p4*2;
        Bs[kk*COUT + o] = Bm[(size_t)(kb+kk)*COUT + o];
      }
    }
    __syncthreads();
    #pragma unroll
    for (int kk = 0; kk < 16; kk++) {
      float4 a4 = *(const float4*)&As[kk*36 + tm*4];
      float4 b4 = *(const float4*)&Bs[kk*COUT + tn*4];
      float av[4] = {a4.x, a4.y, a4.z, a4.w};
      float bv[4] = {b4.x, b4.y, b4.z, b4.w};
      #pragma unroll
      for (int i = 0; i < 4; i++)
        #pragma unroll
        for (int j = 0; j < 4; j++) acc[i][j] = fmaf(av[i], bv[j], acc[i][j]);
    }
    __syncthreads();
  }
  #pragma unroll
  for (int i = 0; i < 4; i++) {
    float4 v = make_float4(acc[i][0], acc[i][1], acc[i][2], acc[i][3]);
    *(float4*)&part[((size_t)ky*GT + m0 + tm*4 + i)*COUT + tn*4] = v;
  }
}

// ---------------- reduce: out = sum(part[0..SPLITK-1]) + bias ----------------
__global__ __launch_bounds__(256) void reduce_kernel(
    const float* __restrict__ part, const float* __restrict__ conv_b,
    float* __restrict__ outp)
{
  int i = blockIdx.x*256 + threadIdx.x;
  float4 s = ((const float4*)conv_b)[i & 31];
  #pragma unroll
  for (int w = 0; w < SPLITK; w++) {
    float4 v = ((const float4*)(part + (size_t)w*GT*COUT))[i];
    s.x += v.x; s.y += v.y; s.z += v.z; s.w += v.w;
  }
  ((float4*)outp)[i] = s;
}

extern "C" void kernel_launch(void* const* d_in, const int* in_sizes, int n_in,
                              void* d_out, int out_size, void* d_ws, size_t ws_size,
                              hipStream_t stream) {
  const float* points   = (const float*)d_in[0];
  const float* features = (const float*)d_in[1];
  const float* lift_w   = (const float*)d_in[2];
  const float* lift_b   = (const float*)d_in[3];
  const float* bn_lift_g= (const float*)d_in[4];
  const float* bn_lift_b= (const float*)d_in[5];
  const float* t1_w     = (const float*)d_in[6];
  const float* t1_b     = (const float*)d_in[7];
  const float* bn1_g    = (const float*)d_in[8];
  const float* bn1_b    = (const float*)d_in[9];
  const float* t2_w     = (const float*)d_in[10];
  const float* t2_b     = (const float*)d_in[11];
  const float* bn2_g    = (const float*)d_in[12];
  const float* bn2_b    = (const float*)d_in[13];
  const float* t3_w     = (const float*)d_in[14];
  const float* t3_b     = (const float*)d_in[15];
  const float* bn3_g    = (const float*)d_in[16];
  const float* bn3_b    = (const float*)d_in[17];
  const float* conv_w   = (const float*)d_in[18];
  const float* conv_b   = (const float*)d_in[19];
  const int*   rep_idx  = (const int*)d_in[20];

  char* ws = (char*)d_ws;
  int*    nb   = (int*)   (ws + 0);          // 256 KB
  float*  p    = (float*) (ws + 262144);     // 768 KB
  float*  Tf   = (float*) (ws + 5242880);    // 20 MB
  float*  wp   = (float*) (ws + 26214400);   // 640 KB
  float*  t1t  = (float*) (ws + 26869760);   // 48 KB
  float*  t2t  = (float*) (ws + 26918912);   // 256 KB
  float*  t3t  = (float*) (ws + 27181056);   // 256 KB
  float*  part = (float*) (ws + 33554432);   // 8 MB (SPLITK=4)
  float4* pts4 = (float4*)(ws + 52428800);   // 256 KB

  float* rep_pos = (float*)d_out;
  float* outp    = (float*)d_out + (size_t)GT*3;

  prep_kernel<<<640, 256, 0, stream>>>(t1_w, t2_w, t3_w, conv_w, points,
                                       t1t, t2t, t3t, wp, pts4);
  knn_kernel<<<GT/8, 512, 0, stream>>>(pts4, rep_idx, nb, p, rep_pos);
  mlp_tf_kernel<<<GT/MGB, 512, 0, stream>>>(p, t1t, t1_b, bn1_g, bn1_b,
                                            t2t, t2_b, bn2_g, bn2_b,
                                            t3t, t3_b, bn3_g, bn3_b,
                                            features, nb,
                                            lift_w, lift_b, bn_lift_g, bn_lift_b,
                                            Tf);
  dim3 ggrid(GT/32, SPLITK);
  gemm_kernel<<<ggrid, 256, 0, stream>>>(Tf, wp, part);
  reduce_kernel<<<(GT*COUT/4)/256, 256, 0, stream>>>(part, conv_b, outp);
}